// Round 4
// baseline (6346.070 us; speedup 1.0000x reference)
//
#include <hip/hip_runtime.h>
#include <cstdint>

#define NN 128000
#define GG 64
#define HH 128
#define EG 1024000
#define EPCV 512000
#define NPG 2000   // nodes per graph

static __device__ __forceinline__ float lrelu(float x){ return x > 0.f ? x : 0.2f*x; }
static __device__ __forceinline__ float f4get(const float4& v, int j){
  return j==0 ? v.x : j==1 ? v.y : j==2 ? v.z : v.w;
}

// ---------------- utility ----------------
__global__ void k_seti(int* p, int n, int v){
  int i = blockIdx.x*blockDim.x + threadIdx.x;
  if(i < n) p[i] = v;
}
__global__ void k_setf(float* p, int n){
  int i = blockIdx.x*blockDim.x + threadIdx.x;
  if(i < n) p[i] = 0.f;
}

// ---------------- CSR build ----------------
__global__ void k_hist(const int* __restrict__ dst, int E, int* __restrict__ counts){
  int i = blockIdx.x*blockDim.x + threadIdx.x;
  if(i < E) atomicAdd(&counts[dst[i]], 1);
}
__global__ void k_scan1(const int* __restrict__ counts, int* __restrict__ rowptr, int* __restrict__ bsums){
  __shared__ int lds[256];
  int t = threadIdx.x, b = blockIdx.x;
  int i0 = b*512 + t*2;
  int s0 = counts[i0], s1 = counts[i0+1];
  int pair = s0 + s1;
  lds[t] = pair; __syncthreads();
  for(int off=1; off<256; off<<=1){
    int v = (t >= off) ? lds[t-off] : 0;
    __syncthreads();
    lds[t] += v;
    __syncthreads();
  }
  int excl = lds[t] - pair;
  rowptr[i0+1] = excl + s0;
  rowptr[i0+2] = excl + pair;
  if(t == 255) bsums[b] = lds[t];
}
__global__ void k_scan2(int* bsums, int nb){
  __shared__ int lds[256];
  int t = threadIdx.x;
  int v = (t < nb) ? bsums[t] : 0;
  lds[t] = v; __syncthreads();
  for(int off=1; off<256; off<<=1){
    int u = (t >= off) ? lds[t-off] : 0;
    __syncthreads();
    lds[t] += u;
    __syncthreads();
  }
  if(t < nb) bsums[t] = lds[t] - v;   // exclusive
}
__global__ void k_scan3(int* __restrict__ rowptr, const int* __restrict__ bsums){
  int i = blockIdx.x*blockDim.x + threadIdx.x;
  if(i >= NN) return;
  rowptr[i+1] += bsums[i >> 9];
  if(i == 0) rowptr[0] = 0;
}
__global__ void k_fill(const int* __restrict__ rowptr, int* __restrict__ fill){
  int i = blockIdx.x*blockDim.x + threadIdx.x;
  if(i < NN) fill[i] = rowptr[i];
}
__global__ void k_scatter(const int* __restrict__ src, const int* __restrict__ dst, int E,
                          int* __restrict__ fill, int* __restrict__ colarr){
  int i = blockIdx.x*blockDim.x + threadIdx.x;
  if(i >= E) return;
  int pos = atomicAdd(&fill[dst[i]], 1);
  colarr[pos] = src[i];
}
__global__ void k_scatter_loops(int* __restrict__ fill, int* __restrict__ colarr){
  int i = blockIdx.x*blockDim.x + threadIdx.x;
  if(i >= NN) return;
  int pos = atomicAdd(&fill[i], 1);
  colarr[pos] = i;
}

// ---------------- aggregation ----------------
// y = x + mean_{j->i} x_j ; fused BN-stat partials (9 per block, no atomics)
__global__ __launch_bounds__(256) void k_segmean3(const float* __restrict__ x, const int* __restrict__ rp,
                           const int* __restrict__ col, float* __restrict__ y,
                           float* __restrict__ part){
  __shared__ float sp[4][9];
  int i = blockIdx.x*256 + threadIdx.x;   // 500*256 == NN exactly
  int b = rp[i], e = rp[i+1];
  float a0=0.f, a1=0.f, a2=0.f;
  for(int j=b; j<e; ++j){
    int s = col[j];
    a0 += x[s*3]; a1 += x[s*3+1]; a2 += x[s*3+2];
  }
  float inv = 1.f / fmaxf((float)(e-b), 1.f);
  float y0 = x[i*3]   + a0*inv;
  float y1 = x[i*3+1] + a1*inv;
  float y2 = x[i*3+2] + a2*inv;
  y[i*3] = y0; y[i*3+1] = y1; y[i*3+2] = y2;
  float p[9] = {y0,y1,y2, y0*y0,y0*y1,y0*y2, y1*y1,y1*y2, y2*y2};
  #pragma unroll
  for(int off=1; off<64; off<<=1)
    #pragma unroll
    for(int j=0;j<9;++j) p[j] += __shfl_xor(p[j], off, 64);
  int lane = threadIdx.x & 63, wv = threadIdx.x >> 6;
  if(lane == 0)
    #pragma unroll
    for(int j=0;j<9;++j) sp[wv][j] = p[j];
  __syncthreads();
  int t = threadIdx.x;
  if(t < 9) part[blockIdx.x*9 + t] = sp[0][t] + sp[1][t] + sp[2][t] + sp[3][t];
}

// y = h + mean (fused self add); one wave per node
__global__ void k_segmean128(const float* __restrict__ h, const int* __restrict__ rp,
                             const int* __restrict__ col, float* __restrict__ y){
  int gid = blockIdx.x*blockDim.x + threadIdx.x;
  int w = gid >> 6, lane = gid & 63;
  if(w >= NN) return;
  int b = rp[w], e = rp[w+1];
  float ax=0.f, ay=0.f;
  for(int j=b; j<e; ++j){
    int s = col[j];
    float2 v = ((const float2*)(h + (size_t)s*HH))[lane];
    ax += v.x; ay += v.y;
  }
  float inv = 1.f / fmaxf((float)(e-b), 1.f);
  float2 self = ((const float2*)(h + (size_t)w*HH))[lane];
  float2 o; o.x = self.x + ax*inv; o.y = self.y + ay*inv;
  ((float2*)(y + (size_t)w*HH))[lane] = o;
}

// GAT softmax-aggregate, single pass (no max-subtraction: logits << 80 here;
// fp32 exp safe, clamp is overflow guard only). Optional fused combine.
__global__ void k_gat_agg(const float* __restrict__ hW, const int* __restrict__ rp,
                          const int* __restrict__ col, const float* __restrict__ sd,
                          const float* __restrict__ ddv, float* __restrict__ out,
                          const float* __restrict__ P, const float* __restrict__ bpc,
                          const float* __restrict__ bmc, float* __restrict__ out2){
  int gid = blockIdx.x*blockDim.x + threadIdx.x;
  int w = gid >> 6, lane = gid & 63;
  if(w >= NN) return;
  int b = rp[w], e = rp[w+1];
  float dv = ddv[w];
  float s = 0.f, ax = 0.f, ay = 0.f;
  for(int j=b; j<e; ++j){
    int sc = col[j];
    float wt = expf(fminf(lrelu(sd[sc] + dv), 80.f));
    float2 v = ((const float2*)(hW + (size_t)sc*HH))[lane];
    s += wt; ax += wt*v.x; ay += wt*v.y;
  }
  float inv = 1.f / (s + 1e-16f);
  ax *= inv; ay *= inv;
  if(P){
    int c = lane*2;
    float2 p = ((const float2*)(P + (size_t)w*HH))[lane];
    float a0 = p.x + bpc[c];   a0 = a0 > 0.f ? a0 : expm1f(a0);
    float a1 = p.y + bpc[c+1]; a1 = a1 > 0.f ? a1 : expm1f(a1);
    float b0 = ax  + bmc[c];   b0 = b0 > 0.f ? b0 : expm1f(b0);
    float b1 = ay  + bmc[c+1]; b1 = b1 > 0.f ? b1 : expm1f(b1);
    float2 o; o.x = 0.5f*(a0+b0); o.y = 0.5f*(a1+b1);
    ((float2*)(out + (size_t)w*HH))[lane] = o;
    if(out2) *(float2*)&out2[(size_t)w*256 + 128 + c] = o;
  } else {
    float2 o; o.x = ax; o.y = ay;
    ((float2*)(out + (size_t)w*HH))[lane] = o;
  }
}

// ---------------- matmuls ----------------
// K=3 matmul with fused attention dots
__global__ __launch_bounds__(256) void k_mm3(const float* __restrict__ A,
        const float* __restrict__ W,
        const float* __restrict__ asrc, const float* __restrict__ adst,
        float* __restrict__ sd, float* __restrict__ dd, float* __restrict__ out){
  int t = threadIdx.x;
  int r = blockIdx.x*8 + (t >> 5);
  int lane = t & 31, c0 = lane*4;
  float a0 = A[r*3], a1 = A[r*3+1], a2 = A[r*3+2];
  float v[4];
  #pragma unroll
  for(int j=0; j<4; ++j){
    int c = c0 + j;
    v[j] = a0*W[c] + a1*W[128+c] + a2*W[256+c];
  }
  *(float4*)&out[(size_t)r*128 + c0] = make_float4(v[0],v[1],v[2],v[3]);
  float s = 0.f, d = 0.f;
  #pragma unroll
  for(int j=0; j<4; ++j){ s += v[j]*asrc[c0+j]; d += v[j]*adst[c0+j]; }
  #pragma unroll
  for(int off=1; off<32; off<<=1){ s += __shfl_xor(s, off, 64); d += __shfl_xor(d, off, 64); }
  if(lane == 0){ sd[r] = s; dd[r] = d; }
}

// ---- K=128 matmul, v3 ----
// Full W[128][128] in LDS (staged once, one barrier). 128-row tile, 256 thr.
// Per thread: 8 rows x 8 cols, but the 8 cols are [cg*4, cg*4+4) U
// [64+cg*4, 64+cg*4+4): 16 lanes at 16B stride -> 2-way bank access (free),
// vs the 4-way conflict of the cg*8 partition.
// A streamed global->reg in 4-k chunks, FOUR-deep pipeline (issue-to-use
// ~1536 cy) to cover L3 first-touch latency.

#define MM_LOAD(BUF, CH) { \
  _Pragma("unroll") \
  for(int rr_=0; rr_<8; ++rr_) BUF[rr_] = pa[rr_*32 + (CH)]; \
  }

#define MM_BN(BUF, K0) if(HASBN){ \
  float4 ba = *(float4*)&sBNa[K0]; \
  float4 bs = *(float4*)&sBNsh[K0]; \
  _Pragma("unroll") \
  for(int rr_=0; rr_<8; ++rr_){ \
    BUF[rr_].x = fmaxf(fmaf(BUF[rr_].x, ba.x, bs.x), 0.f); \
    BUF[rr_].y = fmaxf(fmaf(BUF[rr_].y, ba.y, bs.y), 0.f); \
    BUF[rr_].z = fmaxf(fmaf(BUF[rr_].z, ba.z, bs.z), 0.f); \
    BUF[rr_].w = fmaxf(fmaf(BUF[rr_].w, ba.w, bs.w), 0.f); \
  } }

#define MM_COMPUTE(BUF, CH) { \
  int k0_ = (CH)*4; \
  MM_BN(BUF, k0_); \
  _Pragma("unroll") \
  for(int j_=0; j_<4; ++j_){ \
    float4 w0 = *(float4*)&sW[k0_+j_][c0a]; \
    float4 w1 = *(float4*)&sW[k0_+j_][c0b]; \
    _Pragma("unroll") \
    for(int rr_=0; rr_<8; ++rr_){ \
      float av_ = f4get(BUF[rr_], j_); \
      acc[rr_][0] = fmaf(av_, w0.x, acc[rr_][0]); \
      acc[rr_][1] = fmaf(av_, w0.y, acc[rr_][1]); \
      acc[rr_][2] = fmaf(av_, w0.z, acc[rr_][2]); \
      acc[rr_][3] = fmaf(av_, w0.w, acc[rr_][3]); \
      acc[rr_][4] = fmaf(av_, w1.x, acc[rr_][4]); \
      acc[rr_][5] = fmaf(av_, w1.y, acc[rr_][5]); \
      acc[rr_][6] = fmaf(av_, w1.z, acc[rr_][6]); \
      acc[rr_][7] = fmaf(av_, w1.w, acc[rr_][7]); \
    } \
  } }

template<bool HASBN>
__global__ __launch_bounds__(256,2) void k_mm128_t(
    const float* __restrict__ A,
    const float* __restrict__ bn_a, const float* __restrict__ bn_sh,
    const float* __restrict__ W, const float* __restrict__ bias,
    float* __restrict__ out, float* __restrict__ pool, int pool_mode,
    const float* __restrict__ asrc, const float* __restrict__ adst,
    float* __restrict__ sd, float* __restrict__ dd,
    float* __restrict__ musum, float* __restrict__ sqsum){
  __shared__ float sW[128][128];   // 64 KB, full W
  __shared__ float sBNa[128], sBNsh[128];
  __shared__ float ls[128], lq[128];
  int t = threadIdx.x;
  #pragma unroll
  for(int i=0;i<16;++i){
    int f = i*1024 + t*4;
    *(float4*)&sW[f>>7][f&127] = *(const float4*)&W[f];
  }
  if(HASBN && t < 128){ sBNa[t] = bn_a[t]; sBNsh[t] = bn_sh[t]; }
  if(musum && t < 128){ ls[t] = 0.f; lq[t] = 0.f; }
  int row0 = blockIdx.x*128;
  int rg = t >> 4, cg = t & 15;
  int c0a = cg*4, c0b = 64 + cg*4;
  const float4* pa = (const float4*)(A + (size_t)(row0 + rg*8)*HH);
  float acc[8][8];
  #pragma unroll
  for(int i=0;i<8;++i)
    #pragma unroll
    for(int j=0;j<8;++j) acc[i][j]=0.f;
  float4 aA[8], aB[8], aC[8], aD[8];
  MM_LOAD(aA, 0);
  MM_LOAD(aB, 1);
  MM_LOAD(aC, 2);
  MM_LOAD(aD, 3);
  __syncthreads();                 // the only k-loop-related barrier

  #pragma unroll 1
  for(int cc=0; cc<7; ++cc){
    MM_COMPUTE(aA, 4*cc);   MM_LOAD(aA, 4*cc+4);
    MM_COMPUTE(aB, 4*cc+1); MM_LOAD(aB, 4*cc+5);
    MM_COMPUTE(aC, 4*cc+2); MM_LOAD(aC, 4*cc+6);
    MM_COMPUTE(aD, 4*cc+3); MM_LOAD(aD, 4*cc+7);
  }
  MM_COMPUTE(aA, 28);
  MM_COMPUTE(aB, 29);
  MM_COMPUTE(aC, 30);
  MM_COMPUTE(aD, 31);

  // ---- epilogues (unchanged semantics, split-column indexing) ----
  float as8[8], ad8[8];
  if(asrc){
    #pragma unroll
    for(int j=0;j<8;++j){
      int cj = (j<4) ? c0a+j : c0b+(j-4);
      as8[j] = asrc[cj]; ad8[j] = adst[cj];
    }
  }
  float bb[8];
  #pragma unroll
  for(int j=0;j<8;++j){
    int cj = (j<4) ? c0a+j : c0b+(j-4);
    bb[j] = bias ? bias[cj] : 0.f;
  }
  float cs[8], cq[8];
  #pragma unroll
  for(int j=0;j<8;++j){ cs[j]=0.f; cq[j]=0.f; }
  #pragma unroll
  for(int rr=0; rr<8; ++rr){
    int r = row0 + rg*8 + rr;
    float v[8];
    #pragma unroll
    for(int j=0;j<8;++j) v[j] = acc[rr][j] + bb[j];
    *(float4*)&out[(size_t)r*128 + c0a] = make_float4(v[0],v[1],v[2],v[3]);
    *(float4*)&out[(size_t)r*128 + c0b] = make_float4(v[4],v[5],v[6],v[7]);
    if(pool_mode == 1){
      *(float4*)&pool[(size_t)r*256 + c0a] = make_float4(v[0],v[1],v[2],v[3]);
      *(float4*)&pool[(size_t)r*256 + c0b] = make_float4(v[4],v[5],v[6],v[7]);
    } else if(pool_mode == 2){
      float4 p0 = *(float4*)&pool[(size_t)r*256 + c0a];
      float4 p1 = *(float4*)&pool[(size_t)r*256 + c0b];
      p0.x+=v[0]; p0.y+=v[1]; p0.z+=v[2]; p0.w+=v[3];
      p1.x+=v[4]; p1.y+=v[5]; p1.z+=v[6]; p1.w+=v[7];
      *(float4*)&pool[(size_t)r*256 + c0a] = p0;
      *(float4*)&pool[(size_t)r*256 + c0b] = p1;
    }
    if(musum){
      #pragma unroll
      for(int j=0;j<8;++j){ cs[j] += v[j]; cq[j] += v[j]*v[j]; }
    }
    if(asrc){
      float s = 0.f, d = 0.f;
      #pragma unroll
      for(int j=0;j<8;++j){ s += v[j]*as8[j]; d += v[j]*ad8[j]; }
      #pragma unroll
      for(int off=1; off<16; off<<=1){ s += __shfl_xor(s, off, 64); d += __shfl_xor(d, off, 64); }
      if(cg == 0){ sd[r] = s; dd[r] = d; }
    }
  }
  if(musum){
    #pragma unroll
    for(int j=0;j<8;++j){
      int cj = (j<4) ? c0a+j : c0b+(j-4);
      atomicAdd(&ls[cj], cs[j]); atomicAdd(&lq[cj], cq[j]);
    }
    __syncthreads();
    if(t < 128){ atomicAdd(&musum[t], ls[t]); atomicAdd(&sqsum[t], lq[t]); }
  }
}

// ---------------- GIN layer 0: fully fused ----------------
// Same split-column structure: W2 fully in LDS; the z-operand
// z = relu(BN(y3 @ W1)) computed per-thread in registers (K=3, cheap).
// Zero global loads and zero barriers in the k-loop.
__global__ __launch_bounds__(256,2) void k_gin0(
    const float* __restrict__ y3,
    const float* __restrict__ W1, const float* __restrict__ b1,
    const float* __restrict__ bn_a, const float* __restrict__ bn_sh,
    const float* __restrict__ W2, const float* __restrict__ b2,
    float* __restrict__ outh, float* __restrict__ pool){
  __shared__ float sW[128][128];   // 64 KB, full W2
  __shared__ float sW1[3][128];
  __shared__ float ssb[128];
  int t = threadIdx.x;
  #pragma unroll
  for(int i=0;i<16;++i){
    int f = i*1024 + t*4;
    *(float4*)&sW[f>>7][f&127] = *(const float4*)&W2[f];
  }
  if(t < 128){
    float a = bn_a[t];
    sW1[0][t] = W1[t]*a; sW1[1][t] = W1[128+t]*a; sW1[2][t] = W1[256+t]*a;
    ssb[t] = b1[t]*a + bn_sh[t];
  }
  int row0 = blockIdx.x*128;
  int rg = t >> 4, cg = t & 15;
  int c0a = cg*4, c0b = 64 + cg*4;
  float ya[8], yb[8], yc[8];
  #pragma unroll
  for(int rr=0; rr<8; ++rr){
    const float* yp = y3 + (size_t)(row0 + rg*8 + rr)*3;
    ya[rr] = yp[0]; yb[rr] = yp[1]; yc[rr] = yp[2];
  }
  float acc[8][8];
  #pragma unroll
  for(int i=0;i<8;++i)
    #pragma unroll
    for(int j=0;j<8;++j) acc[i][j]=0.f;
  __syncthreads();

  #pragma unroll 1
  for(int ch=0; ch<32; ++ch){
    int k0 = ch*4;
    float4 wa = *(float4*)&sW1[0][k0];
    float4 wb = *(float4*)&sW1[1][k0];
    float4 wc = *(float4*)&sW1[2][k0];
    float4 sb = *(float4*)&ssb[k0];
    float av[8][4];
    #pragma unroll
    for(int rr=0; rr<8; ++rr){
      #pragma unroll
      for(int j=0; j<4; ++j){
        av[rr][j] = fmaxf(fmaf(ya[rr], f4get(wa,j),
                         fmaf(yb[rr], f4get(wb,j),
                         fmaf(yc[rr], f4get(wc,j), f4get(sb,j)))), 0.f);
      }
    }
    #pragma unroll
    for(int j=0; j<4; ++j){
      float4 w0 = *(float4*)&sW[k0+j][c0a];
      float4 w1 = *(float4*)&sW[k0+j][c0b];
      #pragma unroll
      for(int rr=0; rr<8; ++rr){
        float a = av[rr][j];
        acc[rr][0] = fmaf(a, w0.x, acc[rr][0]);
        acc[rr][1] = fmaf(a, w0.y, acc[rr][1]);
        acc[rr][2] = fmaf(a, w0.z, acc[rr][2]);
        acc[rr][3] = fmaf(a, w0.w, acc[rr][3]);
        acc[rr][4] = fmaf(a, w1.x, acc[rr][4]);
        acc[rr][5] = fmaf(a, w1.y, acc[rr][5]);
        acc[rr][6] = fmaf(a, w1.z, acc[rr][6]);
        acc[rr][7] = fmaf(a, w1.w, acc[rr][7]);
      }
    }
  }
  #pragma unroll
  for(int rr=0; rr<8; ++rr){
    int r = row0 + rg*8 + rr;
    float v[8];
    #pragma unroll
    for(int j=0;j<8;++j){
      int cj = (j<4) ? c0a+j : c0b+(j-4);
      v[j] = acc[rr][j] + b2[cj];
    }
    float4 v0 = make_float4(v[0],v[1],v[2],v[3]);
    float4 v1 = make_float4(v[4],v[5],v[6],v[7]);
    *(float4*)&outh[(size_t)r*128 + c0a] = v0;
    *(float4*)&outh[(size_t)r*128 + c0b] = v1;
    *(float4*)&pool[(size_t)r*256 + c0a] = v0;
    *(float4*)&pool[(size_t)r*256 + c0b] = v1;
  }
}

// ---------------- batchnorm finalize ----------------
// GIN0: reduce 500x9 partials, analytic var through W1
__global__ void k_bnfin3(const float* __restrict__ part,
                         const float* __restrict__ W1, const float* __restrict__ b1,
                         const float* __restrict__ g, const float* __restrict__ beta,
                         float* __restrict__ a, float* __restrict__ sh){
  __shared__ float red[9][128];
  int t = threadIdx.x;
  float acc[9];
  #pragma unroll
  for(int j=0;j<9;++j) acc[j]=0.f;
  for(int i=t; i<500; i+=128)
    #pragma unroll
    for(int j=0;j<9;++j) acc[j] += part[i*9+j];
  #pragma unroll
  for(int j=0;j<9;++j) red[j][t] = acc[j];
  __syncthreads();
  for(int off=64; off; off>>=1){
    if(t < off)
      #pragma unroll
      for(int j=0;j<9;++j) red[j][t] += red[j][t+off];
    __syncthreads();
  }
  int c = t;
  double inv = 1.0/NN;
  double m0=red[0][0]*inv, m1=red[1][0]*inv, m2=red[2][0]*inv;
  double C00=red[3][0]*inv-m0*m0, C01=red[4][0]*inv-m0*m1, C02=red[5][0]*inv-m0*m2;
  double C11=red[6][0]*inv-m1*m1, C12=red[7][0]*inv-m1*m2, C22=red[8][0]*inv-m2*m2;
  double w0=W1[c], w1=W1[128+c], w2=W1[256+c];
  double mu  = m0*w0 + m1*w1 + m2*w2 + (double)b1[c];
  double var = w0*w0*C00 + w1*w1*C11 + w2*w2*C22
             + 2.0*(w0*w1*C01 + w0*w2*C02 + w1*w2*C12);
  double ai = (double)g[c] / sqrt(var + 1e-5);
  a[c]  = (float)ai;
  sh[c] = (float)((double)beta[c] - mu*ai);
}
__global__ void k_bnfin(const float* __restrict__ musum, const float* __restrict__ sqsum,
                        const float* __restrict__ g, const float* __restrict__ beta,
                        float* __restrict__ a, float* __restrict__ sh){
  int c = threadIdx.x;
  float mu  = musum[c] * (1.f/NN);
  float var = sqsum[c] * (1.f/NN) - mu*mu;
  float ai  = g[c] / sqrtf(var + 1e-5f);
  a[c]  = ai;
  sh[c] = beta[c] - mu*ai;
}

// ---------------- pooling / output ----------------
__global__ __launch_bounds__(256) void k_gpool2(const float* __restrict__ h,
                                                float* __restrict__ gpool, float scale){
  __shared__ float s[128];
  int g = blockIdx.x >> 4, chunk = blockIdx.x & 15;
  int t = threadIdx.x, c = t & 127, hh = t >> 7;
  int r0 = g*NPG + chunk*125;
  float sm = 0.f;
  for(int r = r0 + hh; r < r0 + 125; r += 2) sm += h[(size_t)r*128 + c];
  if(hh == 1) s[c] = sm;
  __syncthreads();
  if(hh == 0) atomicAdd(&gpool[g*128 + c], (sm + s[c]) * scale);
}
__global__ void k_write_graph(const float* __restrict__ gpool, const float* __restrict__ gdg,
                              float* __restrict__ out){
  int i = blockIdx.x*256 + threadIdx.x;
  int g = i >> 8, c = i & 255;
  out[(size_t)NN*256 + i] = (c < 128) ? gpool[g*128 + c] : gdg[g*128 + c - 128];
}

// ---------------- launch ----------------
extern "C" void kernel_launch(void* const* d_in, const int* in_sizes, int n_in,
                              void* d_out, int out_size, void* d_ws, size_t ws_size,
                              hipStream_t stream){
  const float* x        = (const float*)d_in[0];
  const int*   ei       = (const int*)d_in[1];
  const int*   ei_pc    = (const int*)d_in[2];
  const int*   ei_mc    = (const int*)d_in[3];
  const float* gin0_W1  = (const float*)d_in[6];
  const float* gin0_b1  = (const float*)d_in[7];
  const float* gin0_g   = (const float*)d_in[8];
  const float* gin0_be  = (const float*)d_in[9];
  const float* gin0_W2  = (const float*)d_in[10];
  const float* gin0_b2  = (const float*)d_in[11];
  const float* ginr_W1  = (const float*)d_in[12];
  const float* ginr_b1  = (const float*)d_in[13];
  const float* ginr_g   = (const float*)d_in[14];
  const float* ginr_be  = (const float*)d_in[15];
  const float* ginr_W2  = (const float*)d_in[16];
  const float* ginr_b2  = (const float*)d_in[17];
  const float* gat0_W   = (const float*)d_in[18];
  const float* gat0_as  = (const float*)d_in[19];
  const float* gat0_ad  = (const float*)d_in[20];
  const float* gat0_b   = (const float*)d_in[21];
  const float* gatr_W   = (const float*)d_in[22];
  const float* gatr_as  = (const float*)d_in[23];
  const float* gatr_ad  = (const float*)d_in[24];
  const float* gatr_b   = (const float*)d_in[25];
  float* out = (float*)d_out;

  float* ws = (float*)d_ws;
  size_t o = 0;
  auto alloc_f = [&](size_t n){ float* p = ws + o; o += (n + 3) & ~(size_t)3; return p; };
  float* bufA   = alloc_f((size_t)NN*HH);
  float* bufB   = alloc_f((size_t)NN*HH);
  float* bufC   = alloc_f((size_t)NN*HH);
  int* rp_gin   = (int*)alloc_f(NN+1);
  int* col_gin  = (int*)alloc_f(EG);
  int* rp_pc    = (int*)alloc_f(NN+1);
  int* col_pc   = (int*)alloc_f(EPCV+NN);
  int* rp_mc    = (int*)alloc_f(NN+1);
  int* col_mc   = (int*)alloc_f(EPCV+NN);
  int* counts   = (int*)alloc_f(NN);
  int* bsums    = (int*)alloc_f(256);
  float* agg3   = alloc_f((size_t)NN*3);
  float* sd     = alloc_f(NN);
  float* dd     = alloc_f(NN);
  float* gpool  = alloc_f(GG*HH);     // gpool+gdg contiguous (one memset)
  float* gdg    = alloc_f(GG*HH);
  float* bnstat = alloc_f(256);
  float* bn_a   = alloc_f(128);
  float* bn_sh  = alloc_f(128);
  float* spart  = alloc_f(500*9 + 4);
  if(ws_size < o*sizeof(float)) return;

  dim3 B(256);
  dim3 gN((NN+255)/256);          // 500
  dim3 gWave(32000);
  dim3 gMM(1000), gMM3(16000);    // 128-row mm tiles
  dim3 gGP(GG*16);

  auto build_csr = [&](const int* s, const int* d, int E, int loops, int* rp, int* colarr){
    k_seti<<<gN, B, 0, stream>>>(counts, NN, loops ? 1 : 0);
    k_hist<<<dim3((E+255)/256), B, 0, stream>>>(d, E, counts);
    k_scan1<<<dim3(250), B, 0, stream>>>(counts, rp, bsums);
    k_scan2<<<dim3(1), B, 0, stream>>>(bsums, 250);
    k_scan3<<<gN, B, 0, stream>>>(rp, bsums);
    k_fill<<<gN, B, 0, stream>>>(rp, counts);
    k_scatter<<<dim3((E+255)/256), B, 0, stream>>>(s, d, E, counts, colarr);
    if(loops) k_scatter_loops<<<gN, B, 0, stream>>>(counts, colarr);
  };
  build_csr(ei,           ei + EG,       EG,   0, rp_gin, col_gin);
  build_csr(ei_pc,        ei_pc + EPCV,  EPCV, 1, rp_pc,  col_pc);
  build_csr(ei_mc,        ei_mc + EPCV,  EPCV, 1, rp_mc,  col_mc);

  k_setf<<<dim3(64), B, 0, stream>>>(gpool, 2*GG*HH);   // gpool + gdg

  // ---- GIN layer 0 (fully fused; BN stats analytic from [N,3] covariance) ----
  k_segmean3<<<gN, B, 0, stream>>>(x, rp_gin, col_gin, agg3, spart);
  k_bnfin3<<<dim3(1), dim3(128), 0, stream>>>(spart, gin0_W1, gin0_b1, gin0_g, gin0_be, bn_a, bn_sh);
  k_gin0<<<gMM, B, 0, stream>>>(agg3, gin0_W1, gin0_b1, bn_a, bn_sh, gin0_W2, gin0_b2, bufA, out);
  k_gpool2<<<gGP, B, 0, stream>>>(bufA, gpool, 1.f/NPG);

  // ---- GIN layers 1..3 ----
  for(int l=0; l<3; ++l){
    k_segmean128<<<gWave, B, 0, stream>>>(bufA, rp_gin, col_gin, bufB);
    k_setf<<<dim3(1), B, 0, stream>>>(bnstat, 256);
    k_mm128_t<false><<<gMM, B, 0, stream>>>(bufB, nullptr, nullptr,
                                   ginr_W1 + (size_t)l*HH*HH, ginr_b1 + l*HH, bufC, nullptr, 0,
                                   nullptr, nullptr, nullptr, nullptr, bnstat, bnstat+128);
    k_bnfin<<<dim3(1), dim3(128), 0, stream>>>(bnstat, bnstat+128, ginr_g + l*HH, ginr_be + l*HH, bn_a, bn_sh);
    k_mm128_t<true><<<gMM, B, 0, stream>>>(bufC, bn_a, bn_sh,
                                   ginr_W2 + (size_t)l*HH*HH, ginr_b2 + l*HH, bufA, out, 2,
                                   nullptr, nullptr, nullptr, nullptr, nullptr, nullptr);
    k_gpool2<<<gGP, B, 0, stream>>>(bufA, gpool, 1.f/NPG);
  }

  // ---- DGHAN layer 0 (in_dim = 3) ----
  k_mm3<<<gMM3, B, 0, stream>>>(x, gat0_W,          gat0_as,      gat0_ad,      sd, dd, bufB);
  k_gat_agg<<<gWave, B, 0, stream>>>(bufB, rp_pc, col_pc, sd, dd, bufC,
                                     nullptr, nullptr, nullptr, nullptr);
  k_mm3<<<gMM3, B, 0, stream>>>(x, gat0_W + 3*HH,   gat0_as + HH, gat0_ad + HH, sd, dd, bufB);
  k_gat_agg<<<gWave, B, 0, stream>>>(bufB, rp_mc, col_mc, sd, dd, bufA,
                                     bufC, gat0_b, gat0_b + HH, nullptr);

  // ---- DGHAN layers 1..3 ----
  for(int l=0; l<3; ++l){
    const float* Wl = gatr_W + (size_t)l*2*HH*HH;
    k_mm128_t<false><<<gMM, B, 0, stream>>>(bufA, nullptr, nullptr, Wl, nullptr, bufB, nullptr, 0,
                                   gatr_as + (size_t)(l*2)*HH, gatr_ad + (size_t)(l*2)*HH, sd, dd,
                                   nullptr, nullptr);
    k_gat_agg<<<gWave, B, 0, stream>>>(bufB, rp_pc, col_pc, sd, dd, bufC,
                                       nullptr, nullptr, nullptr, nullptr);
    k_mm128_t<false><<<gMM, B, 0, stream>>>(bufA, nullptr, nullptr, Wl + HH*HH, nullptr, bufB, nullptr, 0,
                                   gatr_as + (size_t)(l*2+1)*HH, gatr_ad + (size_t)(l*2+1)*HH, sd, dd,
                                   nullptr, nullptr);
    k_gat_agg<<<gWave, B, 0, stream>>>(bufB, rp_mc, col_mc, sd, dd, bufA,
                                       bufC, gatr_b + (size_t)(l*2)*HH, gatr_b + (size_t)(l*2+1)*HH,
                                       (l == 2) ? out : nullptr);
  }

  // ---- finals ----
  k_gpool2<<<gGP, B, 0, stream>>>(bufA, gdg, 1.f/NPG);
  k_write_graph<<<dim3(GG), B, 0, stream>>>(gpool, gdg, out);
}

// Round 5
// 3104.873 us; speedup vs baseline: 2.0439x; 2.0439x over previous
//
#include <hip/hip_runtime.h>
#include <cstdint>

#define NN 128000
#define GG 64
#define HH 128
#define EG 1024000
#define EPCV 512000
#define NPG 2000   // nodes per graph

static __device__ __forceinline__ float lrelu(float x){ return x > 0.f ? x : 0.2f*x; }
static __device__ __forceinline__ float f4get(const float4& v, int j){
  return j==0 ? v.x : j==1 ? v.y : j==2 ? v.z : v.w;
}

// ---------------- utility ----------------
__global__ void k_seti(int* p, int n, int v){
  int i = blockIdx.x*blockDim.x + threadIdx.x;
  if(i < n) p[i] = v;
}
__global__ void k_setf(float* p, int n){
  int i = blockIdx.x*blockDim.x + threadIdx.x;
  if(i < n) p[i] = 0.f;
}

// ---------------- CSR build ----------------
__global__ void k_hist(const int* __restrict__ dst, int E, int* __restrict__ counts){
  int i = blockIdx.x*blockDim.x + threadIdx.x;
  if(i < E) atomicAdd(&counts[dst[i]], 1);
}
__global__ void k_scan1(const int* __restrict__ counts, int* __restrict__ rowptr, int* __restrict__ bsums){
  __shared__ int lds[256];
  int t = threadIdx.x, b = blockIdx.x;
  int i0 = b*512 + t*2;
  int s0 = counts[i0], s1 = counts[i0+1];
  int pair = s0 + s1;
  lds[t] = pair; __syncthreads();
  for(int off=1; off<256; off<<=1){
    int v = (t >= off) ? lds[t-off] : 0;
    __syncthreads();
    lds[t] += v;
    __syncthreads();
  }
  int excl = lds[t] - pair;
  rowptr[i0+1] = excl + s0;
  rowptr[i0+2] = excl + pair;
  if(t == 255) bsums[b] = lds[t];
}
__global__ void k_scan2(int* bsums, int nb){
  __shared__ int lds[256];
  int t = threadIdx.x;
  int v = (t < nb) ? bsums[t] : 0;
  lds[t] = v; __syncthreads();
  for(int off=1; off<256; off<<=1){
    int u = (t >= off) ? lds[t-off] : 0;
    __syncthreads();
    lds[t] += u;
    __syncthreads();
  }
  if(t < nb) bsums[t] = lds[t] - v;   // exclusive
}
__global__ void k_scan3(int* __restrict__ rowptr, const int* __restrict__ bsums){
  int i = blockIdx.x*blockDim.x + threadIdx.x;
  if(i >= NN) return;
  rowptr[i+1] += bsums[i >> 9];
  if(i == 0) rowptr[0] = 0;
}
__global__ void k_fill(const int* __restrict__ rowptr, int* __restrict__ fill){
  int i = blockIdx.x*blockDim.x + threadIdx.x;
  if(i < NN) fill[i] = rowptr[i];
}
__global__ void k_scatter(const int* __restrict__ src, const int* __restrict__ dst, int E,
                          int* __restrict__ fill, int* __restrict__ colarr){
  int i = blockIdx.x*blockDim.x + threadIdx.x;
  if(i >= E) return;
  int pos = atomicAdd(&fill[dst[i]], 1);
  colarr[pos] = src[i];
}
__global__ void k_scatter_loops(int* __restrict__ fill, int* __restrict__ colarr){
  int i = blockIdx.x*blockDim.x + threadIdx.x;
  if(i >= NN) return;
  int pos = atomicAdd(&fill[i], 1);
  colarr[pos] = i;
}

// ---------------- aggregation ----------------
// y = x + mean_{j->i} x_j ; fused BN-stat partials (9 per block, no atomics)
__global__ __launch_bounds__(256) void k_segmean3(const float* __restrict__ x, const int* __restrict__ rp,
                           const int* __restrict__ col, float* __restrict__ y,
                           float* __restrict__ part){
  __shared__ float sp[4][9];
  int i = blockIdx.x*256 + threadIdx.x;   // 500*256 == NN exactly
  int b = rp[i], e = rp[i+1];
  float a0=0.f, a1=0.f, a2=0.f;
  for(int j=b; j<e; ++j){
    int s = col[j];
    a0 += x[s*3]; a1 += x[s*3+1]; a2 += x[s*3+2];
  }
  float inv = 1.f / fmaxf((float)(e-b), 1.f);
  float y0 = x[i*3]   + a0*inv;
  float y1 = x[i*3+1] + a1*inv;
  float y2 = x[i*3+2] + a2*inv;
  y[i*3] = y0; y[i*3+1] = y1; y[i*3+2] = y2;
  float p[9] = {y0,y1,y2, y0*y0,y0*y1,y0*y2, y1*y1,y1*y2, y2*y2};
  #pragma unroll
  for(int off=1; off<64; off<<=1)
    #pragma unroll
    for(int j=0;j<9;++j) p[j] += __shfl_xor(p[j], off, 64);
  int lane = threadIdx.x & 63, wv = threadIdx.x >> 6;
  if(lane == 0)
    #pragma unroll
    for(int j=0;j<9;++j) sp[wv][j] = p[j];
  __syncthreads();
  int t = threadIdx.x;
  if(t < 9) part[blockIdx.x*9 + t] = sp[0][t] + sp[1][t] + sp[2][t] + sp[3][t];
}

// y = h + mean (fused self add); one wave per node
__global__ void k_segmean128(const float* __restrict__ h, const int* __restrict__ rp,
                             const int* __restrict__ col, float* __restrict__ y){
  int gid = blockIdx.x*blockDim.x + threadIdx.x;
  int w = gid >> 6, lane = gid & 63;
  if(w >= NN) return;
  int b = rp[w], e = rp[w+1];
  float ax=0.f, ay=0.f;
  for(int j=b; j<e; ++j){
    int s = col[j];
    float2 v = ((const float2*)(h + (size_t)s*HH))[lane];
    ax += v.x; ay += v.y;
  }
  float inv = 1.f / fmaxf((float)(e-b), 1.f);
  float2 self = ((const float2*)(h + (size_t)w*HH))[lane];
  float2 o; o.x = self.x + ax*inv; o.y = self.y + ay*inv;
  ((float2*)(y + (size_t)w*HH))[lane] = o;
}

// GAT softmax-aggregate, single pass (no max-subtraction: logits << 80 here;
// fp32 exp safe, clamp is overflow guard only). Optional fused combine.
__global__ void k_gat_agg(const float* __restrict__ hW, const int* __restrict__ rp,
                          const int* __restrict__ col, const float* __restrict__ sd,
                          const float* __restrict__ ddv, float* __restrict__ out,
                          const float* __restrict__ P, const float* __restrict__ bpc,
                          const float* __restrict__ bmc, float* __restrict__ out2){
  int gid = blockIdx.x*blockDim.x + threadIdx.x;
  int w = gid >> 6, lane = gid & 63;
  if(w >= NN) return;
  int b = rp[w], e = rp[w+1];
  float dv = ddv[w];
  float s = 0.f, ax = 0.f, ay = 0.f;
  for(int j=b; j<e; ++j){
    int sc = col[j];
    float wt = expf(fminf(lrelu(sd[sc] + dv), 80.f));
    float2 v = ((const float2*)(hW + (size_t)sc*HH))[lane];
    s += wt; ax += wt*v.x; ay += wt*v.y;
  }
  float inv = 1.f / (s + 1e-16f);
  ax *= inv; ay *= inv;
  if(P){
    int c = lane*2;
    float2 p = ((const float2*)(P + (size_t)w*HH))[lane];
    float a0 = p.x + bpc[c];   a0 = a0 > 0.f ? a0 : expm1f(a0);
    float a1 = p.y + bpc[c+1]; a1 = a1 > 0.f ? a1 : expm1f(a1);
    float b0 = ax  + bmc[c];   b0 = b0 > 0.f ? b0 : expm1f(b0);
    float b1 = ay  + bmc[c+1]; b1 = b1 > 0.f ? b1 : expm1f(b1);
    float2 o; o.x = 0.5f*(a0+b0); o.y = 0.5f*(a1+b1);
    ((float2*)(out + (size_t)w*HH))[lane] = o;
    if(out2) *(float2*)&out2[(size_t)w*256 + 128 + c] = o;
  } else {
    float2 o; o.x = ax; o.y = ay;
    ((float2*)(out + (size_t)w*HH))[lane] = o;
  }
}

// ---------------- matmuls ----------------
// K=3 matmul with fused attention dots
__global__ __launch_bounds__(256) void k_mm3(const float* __restrict__ A,
        const float* __restrict__ W,
        const float* __restrict__ asrc, const float* __restrict__ adst,
        float* __restrict__ sd, float* __restrict__ dd, float* __restrict__ out){
  int t = threadIdx.x;
  int r = blockIdx.x*8 + (t >> 5);
  int lane = t & 31, c0 = lane*4;
  float a0 = A[r*3], a1 = A[r*3+1], a2 = A[r*3+2];
  float v[4];
  #pragma unroll
  for(int j=0; j<4; ++j){
    int c = c0 + j;
    v[j] = a0*W[c] + a1*W[128+c] + a2*W[256+c];
  }
  *(float4*)&out[(size_t)r*128 + c0] = make_float4(v[0],v[1],v[2],v[3]);
  float s = 0.f, d = 0.f;
  #pragma unroll
  for(int j=0; j<4; ++j){ s += v[j]*asrc[c0+j]; d += v[j]*adst[c0+j]; }
  #pragma unroll
  for(int off=1; off<32; off<<=1){ s += __shfl_xor(s, off, 64); d += __shfl_xor(d, off, 64); }
  if(lane == 0){ sd[r] = s; dd[r] = d; }
}

// ---- K=128 matmul, v4 ----
// Split-column W partition (verified: 0 bank conflicts in R4).
// PLAIN __launch_bounds__(256): the ",2" waves-per-EU hint made the
// allocator clamp to the 128-reg tier and spill ~1.5GB/dispatch (R4:
// VGPR=128, FETCH 727MB, WRITE 959MB). Plain bounds allocate demand-driven
// (R2: 152 regs for ~158 demand, no spill).
// THREE-deep A pipeline: ~96 buf + 64 acc + ~35 addr ~= 195 regs < 256
// (still 2 waves/SIMD), issue-to-use ~2 chunks ~= 1100 cy covers L3.

#define MM_LOAD(BUF, CH) { \
  _Pragma("unroll") \
  for(int rr_=0; rr_<8; ++rr_) BUF[rr_] = pa[rr_*32 + (CH)]; \
  }

#define MM_BN(BUF, K0) if(HASBN){ \
  float4 ba = *(float4*)&sBNa[K0]; \
  float4 bs = *(float4*)&sBNsh[K0]; \
  _Pragma("unroll") \
  for(int rr_=0; rr_<8; ++rr_){ \
    BUF[rr_].x = fmaxf(fmaf(BUF[rr_].x, ba.x, bs.x), 0.f); \
    BUF[rr_].y = fmaxf(fmaf(BUF[rr_].y, ba.y, bs.y), 0.f); \
    BUF[rr_].z = fmaxf(fmaf(BUF[rr_].z, ba.z, bs.z), 0.f); \
    BUF[rr_].w = fmaxf(fmaf(BUF[rr_].w, ba.w, bs.w), 0.f); \
  } }

#define MM_COMPUTE(BUF, CH) { \
  int k0_ = (CH)*4; \
  MM_BN(BUF, k0_); \
  _Pragma("unroll") \
  for(int j_=0; j_<4; ++j_){ \
    float4 w0 = *(float4*)&sW[k0_+j_][c0a]; \
    float4 w1 = *(float4*)&sW[k0_+j_][c0b]; \
    _Pragma("unroll") \
    for(int rr_=0; rr_<8; ++rr_){ \
      float av_ = f4get(BUF[rr_], j_); \
      acc[rr_][0] = fmaf(av_, w0.x, acc[rr_][0]); \
      acc[rr_][1] = fmaf(av_, w0.y, acc[rr_][1]); \
      acc[rr_][2] = fmaf(av_, w0.z, acc[rr_][2]); \
      acc[rr_][3] = fmaf(av_, w0.w, acc[rr_][3]); \
      acc[rr_][4] = fmaf(av_, w1.x, acc[rr_][4]); \
      acc[rr_][5] = fmaf(av_, w1.y, acc[rr_][5]); \
      acc[rr_][6] = fmaf(av_, w1.z, acc[rr_][6]); \
      acc[rr_][7] = fmaf(av_, w1.w, acc[rr_][7]); \
    } \
  } }

template<bool HASBN>
__global__ __launch_bounds__(256) void k_mm128_t(
    const float* __restrict__ A,
    const float* __restrict__ bn_a, const float* __restrict__ bn_sh,
    const float* __restrict__ W, const float* __restrict__ bias,
    float* __restrict__ out, float* __restrict__ pool, int pool_mode,
    const float* __restrict__ asrc, const float* __restrict__ adst,
    float* __restrict__ sd, float* __restrict__ dd,
    float* __restrict__ musum, float* __restrict__ sqsum){
  __shared__ float sW[128][128];   // 64 KB, full W
  __shared__ float sBNa[128], sBNsh[128];
  __shared__ float ls[128], lq[128];
  int t = threadIdx.x;
  #pragma unroll
  for(int i=0;i<16;++i){
    int f = i*1024 + t*4;
    *(float4*)&sW[f>>7][f&127] = *(const float4*)&W[f];
  }
  if(HASBN && t < 128){ sBNa[t] = bn_a[t]; sBNsh[t] = bn_sh[t]; }
  if(musum && t < 128){ ls[t] = 0.f; lq[t] = 0.f; }
  int row0 = blockIdx.x*128;
  int rg = t >> 4, cg = t & 15;
  int c0a = cg*4, c0b = 64 + cg*4;
  const float4* pa = (const float4*)(A + (size_t)(row0 + rg*8)*HH);
  float acc[8][8];
  #pragma unroll
  for(int i=0;i<8;++i)
    #pragma unroll
    for(int j=0;j<8;++j) acc[i][j]=0.f;
  float4 aA[8], aB[8], aC[8];
  MM_LOAD(aA, 0);
  MM_LOAD(aB, 1);
  MM_LOAD(aC, 2);
  __syncthreads();                 // the only k-loop-related barrier

  #pragma unroll 1
  for(int cc=0; cc<9; ++cc){
    MM_COMPUTE(aA, 3*cc);   MM_LOAD(aA, 3*cc+3);
    MM_COMPUTE(aB, 3*cc+1); MM_LOAD(aB, 3*cc+4);
    MM_COMPUTE(aC, 3*cc+2); MM_LOAD(aC, 3*cc+5);
  }
  // chunks 0..26 computed, loads issued through 29; finish 27..31
  MM_COMPUTE(aA, 27); MM_LOAD(aA, 30);
  MM_COMPUTE(aB, 28); MM_LOAD(aB, 31);
  MM_COMPUTE(aC, 29);
  MM_COMPUTE(aA, 30);
  MM_COMPUTE(aB, 31);

  // ---- epilogues (unchanged semantics, split-column indexing) ----
  float as8[8], ad8[8];
  if(asrc){
    #pragma unroll
    for(int j=0;j<8;++j){
      int cj = (j<4) ? c0a+j : c0b+(j-4);
      as8[j] = asrc[cj]; ad8[j] = adst[cj];
    }
  }
  float bb[8];
  #pragma unroll
  for(int j=0;j<8;++j){
    int cj = (j<4) ? c0a+j : c0b+(j-4);
    bb[j] = bias ? bias[cj] : 0.f;
  }
  float cs[8], cq[8];
  #pragma unroll
  for(int j=0;j<8;++j){ cs[j]=0.f; cq[j]=0.f; }
  #pragma unroll
  for(int rr=0; rr<8; ++rr){
    int r = row0 + rg*8 + rr;
    float v[8];
    #pragma unroll
    for(int j=0;j<8;++j) v[j] = acc[rr][j] + bb[j];
    *(float4*)&out[(size_t)r*128 + c0a] = make_float4(v[0],v[1],v[2],v[3]);
    *(float4*)&out[(size_t)r*128 + c0b] = make_float4(v[4],v[5],v[6],v[7]);
    if(pool_mode == 1){
      *(float4*)&pool[(size_t)r*256 + c0a] = make_float4(v[0],v[1],v[2],v[3]);
      *(float4*)&pool[(size_t)r*256 + c0b] = make_float4(v[4],v[5],v[6],v[7]);
    } else if(pool_mode == 2){
      float4 p0 = *(float4*)&pool[(size_t)r*256 + c0a];
      float4 p1 = *(float4*)&pool[(size_t)r*256 + c0b];
      p0.x+=v[0]; p0.y+=v[1]; p0.z+=v[2]; p0.w+=v[3];
      p1.x+=v[4]; p1.y+=v[5]; p1.z+=v[6]; p1.w+=v[7];
      *(float4*)&pool[(size_t)r*256 + c0a] = p0;
      *(float4*)&pool[(size_t)r*256 + c0b] = p1;
    }
    if(musum){
      #pragma unroll
      for(int j=0;j<8;++j){ cs[j] += v[j]; cq[j] += v[j]*v[j]; }
    }
    if(asrc){
      float s = 0.f, d = 0.f;
      #pragma unroll
      for(int j=0;j<8;++j){ s += v[j]*as8[j]; d += v[j]*ad8[j]; }
      #pragma unroll
      for(int off=1; off<16; off<<=1){ s += __shfl_xor(s, off, 64); d += __shfl_xor(d, off, 64); }
      if(cg == 0){ sd[r] = s; dd[r] = d; }
    }
  }
  if(musum){
    #pragma unroll
    for(int j=0;j<8;++j){
      int cj = (j<4) ? c0a+j : c0b+(j-4);
      atomicAdd(&ls[cj], cs[j]); atomicAdd(&lq[cj], cq[j]);
    }
    __syncthreads();
    if(t < 128){ atomicAdd(&musum[t], ls[t]); atomicAdd(&sqsum[t], lq[t]); }
  }
}

// ---------------- GIN layer 0: fully fused ----------------
// Same split-column structure: W2 fully in LDS; the z-operand
// z = relu(BN(y3 @ W1)) computed per-thread in registers (K=3, cheap).
// Zero global loads and zero barriers in the k-loop. Plain launch bounds
// (see k_mm128_t comment re: spill).
__global__ __launch_bounds__(256) void k_gin0(
    const float* __restrict__ y3,
    const float* __restrict__ W1, const float* __restrict__ b1,
    const float* __restrict__ bn_a, const float* __restrict__ bn_sh,
    const float* __restrict__ W2, const float* __restrict__ b2,
    float* __restrict__ outh, float* __restrict__ pool){
  __shared__ float sW[128][128];   // 64 KB, full W2
  __shared__ float sW1[3][128];
  __shared__ float ssb[128];
  int t = threadIdx.x;
  #pragma unroll
  for(int i=0;i<16;++i){
    int f = i*1024 + t*4;
    *(float4*)&sW[f>>7][f&127] = *(const float4*)&W2[f];
  }
  if(t < 128){
    float a = bn_a[t];
    sW1[0][t] = W1[t]*a; sW1[1][t] = W1[128+t]*a; sW1[2][t] = W1[256+t]*a;
    ssb[t] = b1[t]*a + bn_sh[t];
  }
  int row0 = blockIdx.x*128;
  int rg = t >> 4, cg = t & 15;
  int c0a = cg*4, c0b = 64 + cg*4;
  float ya[8], yb[8], yc[8];
  #pragma unroll
  for(int rr=0; rr<8; ++rr){
    const float* yp = y3 + (size_t)(row0 + rg*8 + rr)*3;
    ya[rr] = yp[0]; yb[rr] = yp[1]; yc[rr] = yp[2];
  }
  float acc[8][8];
  #pragma unroll
  for(int i=0;i<8;++i)
    #pragma unroll
    for(int j=0;j<8;++j) acc[i][j]=0.f;
  __syncthreads();

  #pragma unroll 1
  for(int ch=0; ch<32; ++ch){
    int k0 = ch*4;
    float4 wa = *(float4*)&sW1[0][k0];
    float4 wb = *(float4*)&sW1[1][k0];
    float4 wc = *(float4*)&sW1[2][k0];
    float4 sb = *(float4*)&ssb[k0];
    float av[8][4];
    #pragma unroll
    for(int rr=0; rr<8; ++rr){
      #pragma unroll
      for(int j=0; j<4; ++j){
        av[rr][j] = fmaxf(fmaf(ya[rr], f4get(wa,j),
                         fmaf(yb[rr], f4get(wb,j),
                         fmaf(yc[rr], f4get(wc,j), f4get(sb,j)))), 0.f);
      }
    }
    #pragma unroll
    for(int j=0; j<4; ++j){
      float4 w0 = *(float4*)&sW[k0+j][c0a];
      float4 w1 = *(float4*)&sW[k0+j][c0b];
      #pragma unroll
      for(int rr=0; rr<8; ++rr){
        float a = av[rr][j];
        acc[rr][0] = fmaf(a, w0.x, acc[rr][0]);
        acc[rr][1] = fmaf(a, w0.y, acc[rr][1]);
        acc[rr][2] = fmaf(a, w0.z, acc[rr][2]);
        acc[rr][3] = fmaf(a, w0.w, acc[rr][3]);
        acc[rr][4] = fmaf(a, w1.x, acc[rr][4]);
        acc[rr][5] = fmaf(a, w1.y, acc[rr][5]);
        acc[rr][6] = fmaf(a, w1.z, acc[rr][6]);
        acc[rr][7] = fmaf(a, w1.w, acc[rr][7]);
      }
    }
  }
  #pragma unroll
  for(int rr=0; rr<8; ++rr){
    int r = row0 + rg*8 + rr;
    float v[8];
    #pragma unroll
    for(int j=0;j<8;++j){
      int cj = (j<4) ? c0a+j : c0b+(j-4);
      v[j] = acc[rr][j] + b2[cj];
    }
    float4 v0 = make_float4(v[0],v[1],v[2],v[3]);
    float4 v1 = make_float4(v[4],v[5],v[6],v[7]);
    *(float4*)&outh[(size_t)r*128 + c0a] = v0;
    *(float4*)&outh[(size_t)r*128 + c0b] = v1;
    *(float4*)&pool[(size_t)r*256 + c0a] = v0;
    *(float4*)&pool[(size_t)r*256 + c0b] = v1;
  }
}

// ---------------- batchnorm finalize ----------------
// GIN0: reduce 500x9 partials, analytic var through W1
__global__ void k_bnfin3(const float* __restrict__ part,
                         const float* __restrict__ W1, const float* __restrict__ b1,
                         const float* __restrict__ g, const float* __restrict__ beta,
                         float* __restrict__ a, float* __restrict__ sh){
  __shared__ float red[9][128];
  int t = threadIdx.x;
  float acc[9];
  #pragma unroll
  for(int j=0;j<9;++j) acc[j]=0.f;
  for(int i=t; i<500; i+=128)
    #pragma unroll
    for(int j=0;j<9;++j) acc[j] += part[i*9+j];
  #pragma unroll
  for(int j=0;j<9;++j) red[j][t] = acc[j];
  __syncthreads();
  for(int off=64; off; off>>=1){
    if(t < off)
      #pragma unroll
      for(int j=0;j<9;++j) red[j][t] += red[j][t+off];
    __syncthreads();
  }
  int c = t;
  double inv = 1.0/NN;
  double m0=red[0][0]*inv, m1=red[1][0]*inv, m2=red[2][0]*inv;
  double C00=red[3][0]*inv-m0*m0, C01=red[4][0]*inv-m0*m1, C02=red[5][0]*inv-m0*m2;
  double C11=red[6][0]*inv-m1*m1, C12=red[7][0]*inv-m1*m2, C22=red[8][0]*inv-m2*m2;
  double w0=W1[c], w1=W1[128+c], w2=W1[256+c];
  double mu  = m0*w0 + m1*w1 + m2*w2 + (double)b1[c];
  double var = w0*w0*C00 + w1*w1*C11 + w2*w2*C22
             + 2.0*(w0*w1*C01 + w0*w2*C02 + w1*w2*C12);
  double ai = (double)g[c] / sqrt(var + 1e-5);
  a[c]  = (float)ai;
  sh[c] = (float)((double)beta[c] - mu*ai);
}
__global__ void k_bnfin(const float* __restrict__ musum, const float* __restrict__ sqsum,
                        const float* __restrict__ g, const float* __restrict__ beta,
                        float* __restrict__ a, float* __restrict__ sh){
  int c = threadIdx.x;
  float mu  = musum[c] * (1.f/NN);
  float var = sqsum[c] * (1.f/NN) - mu*mu;
  float ai  = g[c] / sqrtf(var + 1e-5f);
  a[c]  = ai;
  sh[c] = beta[c] - mu*ai;
}

// ---------------- pooling / output ----------------
__global__ __launch_bounds__(256) void k_gpool2(const float* __restrict__ h,
                                                float* __restrict__ gpool, float scale){
  __shared__ float s[128];
  int g = blockIdx.x >> 4, chunk = blockIdx.x & 15;
  int t = threadIdx.x, c = t & 127, hh = t >> 7;
  int r0 = g*NPG + chunk*125;
  float sm = 0.f;
  for(int r = r0 + hh; r < r0 + 125; r += 2) sm += h[(size_t)r*128 + c];
  if(hh == 1) s[c] = sm;
  __syncthreads();
  if(hh == 0) atomicAdd(&gpool[g*128 + c], (sm + s[c]) * scale);
}
__global__ void k_write_graph(const float* __restrict__ gpool, const float* __restrict__ gdg,
                              float* __restrict__ out){
  int i = blockIdx.x*256 + threadIdx.x;
  int g = i >> 8, c = i & 255;
  out[(size_t)NN*256 + i] = (c < 128) ? gpool[g*128 + c] : gdg[g*128 + c - 128];
}

// ---------------- launch ----------------
extern "C" void kernel_launch(void* const* d_in, const int* in_sizes, int n_in,
                              void* d_out, int out_size, void* d_ws, size_t ws_size,
                              hipStream_t stream){
  const float* x        = (const float*)d_in[0];
  const int*   ei       = (const int*)d_in[1];
  const int*   ei_pc    = (const int*)d_in[2];
  const int*   ei_mc    = (const int*)d_in[3];
  const float* gin0_W1  = (const float*)d_in[6];
  const float* gin0_b1  = (const float*)d_in[7];
  const float* gin0_g   = (const float*)d_in[8];
  const float* gin0_be  = (const float*)d_in[9];
  const float* gin0_W2  = (const float*)d_in[10];
  const float* gin0_b2  = (const float*)d_in[11];
  const float* ginr_W1  = (const float*)d_in[12];
  const float* ginr_b1  = (const float*)d_in[13];
  const float* ginr_g   = (const float*)d_in[14];
  const float* ginr_be  = (const float*)d_in[15];
  const float* ginr_W2  = (const float*)d_in[16];
  const float* ginr_b2  = (const float*)d_in[17];
  const float* gat0_W   = (const float*)d_in[18];
  const float* gat0_as  = (const float*)d_in[19];
  const float* gat0_ad  = (const float*)d_in[20];
  const float* gat0_b   = (const float*)d_in[21];
  const float* gatr_W   = (const float*)d_in[22];
  const float* gatr_as  = (const float*)d_in[23];
  const float* gatr_ad  = (const float*)d_in[24];
  const float* gatr_b   = (const float*)d_in[25];
  float* out = (float*)d_out;

  float* ws = (float*)d_ws;
  size_t o = 0;
  auto alloc_f = [&](size_t n){ float* p = ws + o; o += (n + 3) & ~(size_t)3; return p; };
  float* bufA   = alloc_f((size_t)NN*HH);
  float* bufB   = alloc_f((size_t)NN*HH);
  float* bufC   = alloc_f((size_t)NN*HH);
  int* rp_gin   = (int*)alloc_f(NN+1);
  int* col_gin  = (int*)alloc_f(EG);
  int* rp_pc    = (int*)alloc_f(NN+1);
  int* col_pc   = (int*)alloc_f(EPCV+NN);
  int* rp_mc    = (int*)alloc_f(NN+1);
  int* col_mc   = (int*)alloc_f(EPCV+NN);
  int* counts   = (int*)alloc_f(NN);
  int* bsums    = (int*)alloc_f(256);
  float* agg3   = alloc_f((size_t)NN*3);
  float* sd     = alloc_f(NN);
  float* dd     = alloc_f(NN);
  float* gpool  = alloc_f(GG*HH);     // gpool+gdg contiguous (one memset)
  float* gdg    = alloc_f(GG*HH);
  float* bnstat = alloc_f(256);
  float* bn_a   = alloc_f(128);
  float* bn_sh  = alloc_f(128);
  float* spart  = alloc_f(500*9 + 4);
  if(ws_size < o*sizeof(float)) return;

  dim3 B(256);
  dim3 gN((NN+255)/256);          // 500
  dim3 gWave(32000);
  dim3 gMM(1000), gMM3(16000);    // 128-row mm tiles
  dim3 gGP(GG*16);

  auto build_csr = [&](const int* s, const int* d, int E, int loops, int* rp, int* colarr){
    k_seti<<<gN, B, 0, stream>>>(counts, NN, loops ? 1 : 0);
    k_hist<<<dim3((E+255)/256), B, 0, stream>>>(d, E, counts);
    k_scan1<<<dim3(250), B, 0, stream>>>(counts, rp, bsums);
    k_scan2<<<dim3(1), B, 0, stream>>>(bsums, 250);
    k_scan3<<<gN, B, 0, stream>>>(rp, bsums);
    k_fill<<<gN, B, 0, stream>>>(rp, counts);
    k_scatter<<<dim3((E+255)/256), B, 0, stream>>>(s, d, E, counts, colarr);
    if(loops) k_scatter_loops<<<gN, B, 0, stream>>>(counts, colarr);
  };
  build_csr(ei,           ei + EG,       EG,   0, rp_gin, col_gin);
  build_csr(ei_pc,        ei_pc + EPCV,  EPCV, 1, rp_pc,  col_pc);
  build_csr(ei_mc,        ei_mc + EPCV,  EPCV, 1, rp_mc,  col_mc);

  k_setf<<<dim3(64), B, 0, stream>>>(gpool, 2*GG*HH);   // gpool + gdg

  // ---- GIN layer 0 (fully fused; BN stats analytic from [N,3] covariance) ----
  k_segmean3<<<gN, B, 0, stream>>>(x, rp_gin, col_gin, agg3, spart);
  k_bnfin3<<<dim3(1), dim3(128), 0, stream>>>(spart, gin0_W1, gin0_b1, gin0_g, gin0_be, bn_a, bn_sh);
  k_gin0<<<gMM, B, 0, stream>>>(agg3, gin0_W1, gin0_b1, bn_a, bn_sh, gin0_W2, gin0_b2, bufA, out);
  k_gpool2<<<gGP, B, 0, stream>>>(bufA, gpool, 1.f/NPG);

  // ---- GIN layers 1..3 ----
  for(int l=0; l<3; ++l){
    k_segmean128<<<gWave, B, 0, stream>>>(bufA, rp_gin, col_gin, bufB);
    k_setf<<<dim3(1), B, 0, stream>>>(bnstat, 256);
    k_mm128_t<false><<<gMM, B, 0, stream>>>(bufB, nullptr, nullptr,
                                   ginr_W1 + (size_t)l*HH*HH, ginr_b1 + l*HH, bufC, nullptr, 0,
                                   nullptr, nullptr, nullptr, nullptr, bnstat, bnstat+128);
    k_bnfin<<<dim3(1), dim3(128), 0, stream>>>(bnstat, bnstat+128, ginr_g + l*HH, ginr_be + l*HH, bn_a, bn_sh);
    k_mm128_t<true><<<gMM, B, 0, stream>>>(bufC, bn_a, bn_sh,
                                   ginr_W2 + (size_t)l*HH*HH, ginr_b2 + l*HH, bufA, out, 2,
                                   nullptr, nullptr, nullptr, nullptr, nullptr, nullptr);
    k_gpool2<<<gGP, B, 0, stream>>>(bufA, gpool, 1.f/NPG);
  }

  // ---- DGHAN layer 0 (in_dim = 3) ----
  k_mm3<<<gMM3, B, 0, stream>>>(x, gat0_W,          gat0_as,      gat0_ad,      sd, dd, bufB);
  k_gat_agg<<<gWave, B, 0, stream>>>(bufB, rp_pc, col_pc, sd, dd, bufC,
                                     nullptr, nullptr, nullptr, nullptr);
  k_mm3<<<gMM3, B, 0, stream>>>(x, gat0_W + 3*HH,   gat0_as + HH, gat0_ad + HH, sd, dd, bufB);
  k_gat_agg<<<gWave, B, 0, stream>>>(bufB, rp_mc, col_mc, sd, dd, bufA,
                                     bufC, gat0_b, gat0_b + HH, nullptr);

  // ---- DGHAN layers 1..3 ----
  for(int l=0; l<3; ++l){
    const float* Wl = gatr_W + (size_t)l*2*HH*HH;
    k_mm128_t<false><<<gMM, B, 0, stream>>>(bufA, nullptr, nullptr, Wl, nullptr, bufB, nullptr, 0,
                                   gatr_as + (size_t)(l*2)*HH, gatr_ad + (size_t)(l*2)*HH, sd, dd,
                                   nullptr, nullptr);
    k_gat_agg<<<gWave, B, 0, stream>>>(bufB, rp_pc, col_pc, sd, dd, bufC,
                                       nullptr, nullptr, nullptr, nullptr);
    k_mm128_t<false><<<gMM, B, 0, stream>>>(bufA, nullptr, nullptr, Wl + HH*HH, nullptr, bufB, nullptr, 0,
                                   gatr_as + (size_t)(l*2+1)*HH, gatr_ad + (size_t)(l*2+1)*HH, sd, dd,
                                   nullptr, nullptr);
    k_gat_agg<<<gWave, B, 0, stream>>>(bufB, rp_mc, col_mc, sd, dd, bufA,
                                       bufC, gatr_b + (size_t)(l*2)*HH, gatr_b + (size_t)(l*2+1)*HH,
                                       (l == 2) ? out : nullptr);
  }

  // ---- finals ----
  k_gpool2<<<gGP, B, 0, stream>>>(bufA, gdg, 1.f/NPG);
  k_write_graph<<<dim3(GG), B, 0, stream>>>(gpool, gdg, out);
}

// Round 6
// 2653.042 us; speedup vs baseline: 2.3920x; 1.1703x over previous
//
#include <hip/hip_runtime.h>
#include <cstdint>

#define NN 128000
#define GG 64
#define HH 128
#define EG 1024000
#define EPCV 512000
#define NPG 2000   // nodes per graph

static __device__ __forceinline__ float lrelu(float x){ return x > 0.f ? x : 0.2f*x; }
static __device__ __forceinline__ float f4get(const float4& v, int j){
  return j==0 ? v.x : j==1 ? v.y : j==2 ? v.z : v.w;
}

// ---------------- utility ----------------
__global__ void k_seti(int* p, int n, int v){
  int i = blockIdx.x*blockDim.x + threadIdx.x;
  if(i < n) p[i] = v;
}
__global__ void k_setf(float* p, int n){
  int i = blockIdx.x*blockDim.x + threadIdx.x;
  if(i < n) p[i] = 0.f;
}

// ---------------- CSR build ----------------
__global__ void k_hist(const int* __restrict__ dst, int E, int* __restrict__ counts){
  int i = blockIdx.x*blockDim.x + threadIdx.x;
  if(i < E) atomicAdd(&counts[dst[i]], 1);
}
__global__ void k_scan1(const int* __restrict__ counts, int* __restrict__ rowptr, int* __restrict__ bsums){
  __shared__ int lds[256];
  int t = threadIdx.x, b = blockIdx.x;
  int i0 = b*512 + t*2;
  int s0 = counts[i0], s1 = counts[i0+1];
  int pair = s0 + s1;
  lds[t] = pair; __syncthreads();
  for(int off=1; off<256; off<<=1){
    int v = (t >= off) ? lds[t-off] : 0;
    __syncthreads();
    lds[t] += v;
    __syncthreads();
  }
  int excl = lds[t] - pair;
  rowptr[i0+1] = excl + s0;
  rowptr[i0+2] = excl + pair;
  if(t == 255) bsums[b] = lds[t];
}
__global__ void k_scan2(int* bsums, int nb){
  __shared__ int lds[256];
  int t = threadIdx.x;
  int v = (t < nb) ? bsums[t] : 0;
  lds[t] = v; __syncthreads();
  for(int off=1; off<256; off<<=1){
    int u = (t >= off) ? lds[t-off] : 0;
    __syncthreads();
    lds[t] += u;
    __syncthreads();
  }
  if(t < nb) bsums[t] = lds[t] - v;   // exclusive
}
__global__ void k_scan3(int* __restrict__ rowptr, const int* __restrict__ bsums){
  int i = blockIdx.x*blockDim.x + threadIdx.x;
  if(i >= NN) return;
  rowptr[i+1] += bsums[i >> 9];
  if(i == 0) rowptr[0] = 0;
}
__global__ void k_fill(const int* __restrict__ rowptr, int* __restrict__ fill){
  int i = blockIdx.x*blockDim.x + threadIdx.x;
  if(i < NN) fill[i] = rowptr[i];
}
__global__ void k_scatter(const int* __restrict__ src, const int* __restrict__ dst, int E,
                          int* __restrict__ fill, int* __restrict__ colarr){
  int i = blockIdx.x*blockDim.x + threadIdx.x;
  if(i >= E) return;
  int pos = atomicAdd(&fill[dst[i]], 1);
  colarr[pos] = src[i];
}
__global__ void k_scatter_loops(int* __restrict__ fill, int* __restrict__ colarr){
  int i = blockIdx.x*blockDim.x + threadIdx.x;
  if(i >= NN) return;
  int pos = atomicAdd(&fill[i], 1);
  colarr[pos] = i;
}

// ---------------- aggregation ----------------
// y = x + mean_{j->i} x_j ; fused BN-stat partials (9 per block, no atomics)
__global__ __launch_bounds__(256) void k_segmean3(const float* __restrict__ x, const int* __restrict__ rp,
                           const int* __restrict__ col, float* __restrict__ y,
                           float* __restrict__ part){
  __shared__ float sp[4][9];
  int i = blockIdx.x*256 + threadIdx.x;   // 500*256 == NN exactly
  int b = rp[i], e = rp[i+1];
  float a0=0.f, a1=0.f, a2=0.f;
  for(int j=b; j<e; ++j){
    int s = col[j];
    a0 += x[s*3]; a1 += x[s*3+1]; a2 += x[s*3+2];
  }
  float inv = 1.f / fmaxf((float)(e-b), 1.f);
  float y0 = x[i*3]   + a0*inv;
  float y1 = x[i*3+1] + a1*inv;
  float y2 = x[i*3+2] + a2*inv;
  y[i*3] = y0; y[i*3+1] = y1; y[i*3+2] = y2;
  float p[9] = {y0,y1,y2, y0*y0,y0*y1,y0*y2, y1*y1,y1*y2, y2*y2};
  #pragma unroll
  for(int off=1; off<64; off<<=1)
    #pragma unroll
    for(int j=0;j<9;++j) p[j] += __shfl_xor(p[j], off, 64);
  int lane = threadIdx.x & 63, wv = threadIdx.x >> 6;
  if(lane == 0)
    #pragma unroll
    for(int j=0;j<9;++j) sp[wv][j] = p[j];
  __syncthreads();
  int t = threadIdx.x;
  if(t < 9) part[blockIdx.x*9 + t] = sp[0][t] + sp[1][t] + sp[2][t] + sp[3][t];
}

// y = h + mean (fused self add); one wave per node
__global__ void k_segmean128(const float* __restrict__ h, const int* __restrict__ rp,
                             const int* __restrict__ col, float* __restrict__ y){
  int gid = blockIdx.x*blockDim.x + threadIdx.x;
  int w = gid >> 6, lane = gid & 63;
  if(w >= NN) return;
  int b = rp[w], e = rp[w+1];
  float ax=0.f, ay=0.f;
  for(int j=b; j<e; ++j){
    int s = col[j];
    float2 v = ((const float2*)(h + (size_t)s*HH))[lane];
    ax += v.x; ay += v.y;
  }
  float inv = 1.f / fmaxf((float)(e-b), 1.f);
  float2 self = ((const float2*)(h + (size_t)w*HH))[lane];
  float2 o; o.x = self.x + ax*inv; o.y = self.y + ay*inv;
  ((float2*)(y + (size_t)w*HH))[lane] = o;
}

// GAT softmax-aggregate, single pass (no max-subtraction: logits << 80 here;
// fp32 exp safe, clamp is overflow guard only). Optional fused combine.
__global__ void k_gat_agg(const float* __restrict__ hW, const int* __restrict__ rp,
                          const int* __restrict__ col, const float* __restrict__ sd,
                          const float* __restrict__ ddv, float* __restrict__ out,
                          const float* __restrict__ P, const float* __restrict__ bpc,
                          const float* __restrict__ bmc, float* __restrict__ out2){
  int gid = blockIdx.x*blockDim.x + threadIdx.x;
  int w = gid >> 6, lane = gid & 63;
  if(w >= NN) return;
  int b = rp[w], e = rp[w+1];
  float dv = ddv[w];
  float s = 0.f, ax = 0.f, ay = 0.f;
  for(int j=b; j<e; ++j){
    int sc = col[j];
    float wt = expf(fminf(lrelu(sd[sc] + dv), 80.f));
    float2 v = ((const float2*)(hW + (size_t)sc*HH))[lane];
    s += wt; ax += wt*v.x; ay += wt*v.y;
  }
  float inv = 1.f / (s + 1e-16f);
  ax *= inv; ay *= inv;
  if(P){
    int c = lane*2;
    float2 p = ((const float2*)(P + (size_t)w*HH))[lane];
    float a0 = p.x + bpc[c];   a0 = a0 > 0.f ? a0 : expm1f(a0);
    float a1 = p.y + bpc[c+1]; a1 = a1 > 0.f ? a1 : expm1f(a1);
    float b0 = ax  + bmc[c];   b0 = b0 > 0.f ? b0 : expm1f(b0);
    float b1 = ay  + bmc[c+1]; b1 = b1 > 0.f ? b1 : expm1f(b1);
    float2 o; o.x = 0.5f*(a0+b0); o.y = 0.5f*(a1+b1);
    ((float2*)(out + (size_t)w*HH))[lane] = o;
    if(out2) *(float2*)&out2[(size_t)w*256 + 128 + c] = o;
  } else {
    float2 o; o.x = ax; o.y = ay;
    ((float2*)(out + (size_t)w*HH))[lane] = o;
  }
}

// ---------------- matmuls ----------------
// K=3 matmul with fused attention dots
__global__ __launch_bounds__(256) void k_mm3(const float* __restrict__ A,
        const float* __restrict__ W,
        const float* __restrict__ asrc, const float* __restrict__ adst,
        float* __restrict__ sd, float* __restrict__ dd, float* __restrict__ out){
  int t = threadIdx.x;
  int r = blockIdx.x*8 + (t >> 5);
  int lane = t & 31, c0 = lane*4;
  float a0 = A[r*3], a1 = A[r*3+1], a2 = A[r*3+2];
  float v[4];
  #pragma unroll
  for(int j=0; j<4; ++j){
    int c = c0 + j;
    v[j] = a0*W[c] + a1*W[128+c] + a2*W[256+c];
  }
  *(float4*)&out[(size_t)r*128 + c0] = make_float4(v[0],v[1],v[2],v[3]);
  float s = 0.f, d = 0.f;
  #pragma unroll
  for(int j=0; j<4; ++j){ s += v[j]*asrc[c0+j]; d += v[j]*adst[c0+j]; }
  #pragma unroll
  for(int off=1; off<32; off<<=1){ s += __shfl_xor(s, off, 64); d += __shfl_xor(d, off, 64); }
  if(lane == 0){ sd[r] = s; dd[r] = d; }
}

// ---- K=128 matmul, v5: LDS-deduped A ----
// Diagnosis chain: R2/R5 pinned at ~150us, VALUBusy ~35%, 0 conflicts,
// deep prefetch ineffective -> VMEM front-end: the per-thread A loads had
// 16 lanes/group issuing IDENTICAL addresses (pa depends on rg only), so
// each global_load_dwordx4 delivered 64B unique -> 1024 redundant VMEM
// wave-instrs/block. R4's spill accident proved 3.6TB/s is reachable,
// so issue-rate, not bandwidth, is the limit.
// v5: coalesced A stage through LDS. Thread t loads ONE float4 of the
// chunk (row t>>1, k-half t&1) -> ds_write into double-buffered
// sA[2][8k][128rows]. 16 VMEM instrs/thread (was 256). One barrier per
// chunk: write(ch,b) -> barrier -> compute(ch,b); next write goes to b^1
// whose readers (compute ch-1) all finished before their write(ch)+barrier.
// Writes: bank = row%32, 2 lanes/bank = free. Reads: 4 distinct 32B
// segments, 16-lane broadcast = conflict-free. W split-column (R4: 0 conf).
// BN folded into the stage (4 vals/thread/chunk). LDS 74KB -> 2 blocks/CU.

#define MM_COMPUTE_CH(BUFIDX, K0) { \
  _Pragma("unroll") \
  for(int j_=0; j_<8; ++j_){ \
    float4 a0 = *(float4*)&sA[BUFIDX][j_][rg8]; \
    float4 a1 = *(float4*)&sA[BUFIDX][j_][rg8+4]; \
    float4 w0 = *(float4*)&sW[(K0)+j_][c0a]; \
    float4 w1 = *(float4*)&sW[(K0)+j_][c0b]; \
    float ar[8] = {a0.x,a0.y,a0.z,a0.w,a1.x,a1.y,a1.z,a1.w}; \
    _Pragma("unroll") \
    for(int rr_=0; rr_<8; ++rr_){ \
      acc[rr_][0] = fmaf(ar[rr_], w0.x, acc[rr_][0]); \
      acc[rr_][1] = fmaf(ar[rr_], w0.y, acc[rr_][1]); \
      acc[rr_][2] = fmaf(ar[rr_], w0.z, acc[rr_][2]); \
      acc[rr_][3] = fmaf(ar[rr_], w0.w, acc[rr_][3]); \
      acc[rr_][4] = fmaf(ar[rr_], w1.x, acc[rr_][4]); \
      acc[rr_][5] = fmaf(ar[rr_], w1.y, acc[rr_][5]); \
      acc[rr_][6] = fmaf(ar[rr_], w1.z, acc[rr_][6]); \
      acc[rr_][7] = fmaf(ar[rr_], w1.w, acc[rr_][7]); \
    } \
  } }

template<bool HASBN>
__global__ __launch_bounds__(256) void k_mm128_t(
    const float* __restrict__ A,
    const float* __restrict__ bn_a, const float* __restrict__ bn_sh,
    const float* __restrict__ W, const float* __restrict__ bias,
    float* __restrict__ out, float* __restrict__ pool, int pool_mode,
    const float* __restrict__ asrc, const float* __restrict__ adst,
    float* __restrict__ sd, float* __restrict__ dd,
    float* __restrict__ musum, float* __restrict__ sqsum){
  __shared__ float sW[128][128];     // 64 KB, full W
  __shared__ float sA[2][8][128];    // 8 KB, double-buffered A chunk (k-major)
  __shared__ float sBNa[128], sBNsh[128];
  __shared__ float ls[128], lq[128];
  int t = threadIdx.x;
  #pragma unroll
  for(int i=0;i<16;++i){
    int f = i*1024 + t*4;
    *(float4*)&sW[f>>7][f&127] = *(const float4*)&W[f];
  }
  if(HASBN && t < 128){ sBNa[t] = bn_a[t]; sBNsh[t] = bn_sh[t]; }
  if(musum && t < 128){ ls[t] = 0.f; lq[t] = 0.f; }
  int row0 = blockIdx.x*128;
  int rg = t >> 4, cg = t & 15;
  int rg8 = rg*8;
  int c0a = cg*4, c0b = 64 + cg*4;
  int lrow = t >> 1, lk = (t & 1)*4;   // staging: row, k-half within chunk
  const float* ap = A + (size_t)(row0 + lrow)*HH + lk;
  float acc[8][8];
  #pragma unroll
  for(int i=0;i<8;++i)
    #pragma unroll
    for(int j=0;j<8;++j) acc[i][j]=0.f;
  float4 lv = *(const float4*)ap;      // chunk 0
  __syncthreads();                     // W/BN staged; sA untouched yet

  #pragma unroll 1
  for(int ch=0; ch<16; ++ch){
    int b = ch & 1;
    float4 nlv = lv;
    if(ch < 15) nlv = *(const float4*)(ap + (ch+1)*8);   // prefetch next chunk
    float4 sv = lv;
    if(HASBN){
      float4 ba = *(float4*)&sBNa[ch*8 + lk];
      float4 bs = *(float4*)&sBNsh[ch*8 + lk];
      sv.x = fmaxf(fmaf(sv.x, ba.x, bs.x), 0.f);
      sv.y = fmaxf(fmaf(sv.y, ba.y, bs.y), 0.f);
      sv.z = fmaxf(fmaf(sv.z, ba.z, bs.z), 0.f);
      sv.w = fmaxf(fmaf(sv.w, ba.w, bs.w), 0.f);
    }
    sA[b][lk  ][lrow] = sv.x;
    sA[b][lk+1][lrow] = sv.y;
    sA[b][lk+2][lrow] = sv.z;
    sA[b][lk+3][lrow] = sv.w;
    __syncthreads();                   // writes of buf b visible
    MM_COMPUTE_CH(b, ch*8);
    lv = nlv;
  }

  // ---- epilogues (unchanged semantics, split-column indexing) ----
  float as8[8], ad8[8];
  if(asrc){
    #pragma unroll
    for(int j=0;j<8;++j){
      int cj = (j<4) ? c0a+j : c0b+(j-4);
      as8[j] = asrc[cj]; ad8[j] = adst[cj];
    }
  }
  float bb[8];
  #pragma unroll
  for(int j=0;j<8;++j){
    int cj = (j<4) ? c0a+j : c0b+(j-4);
    bb[j] = bias ? bias[cj] : 0.f;
  }
  float cs[8], cq[8];
  #pragma unroll
  for(int j=0;j<8;++j){ cs[j]=0.f; cq[j]=0.f; }
  #pragma unroll
  for(int rr=0; rr<8; ++rr){
    int r = row0 + rg8 + rr;
    float v[8];
    #pragma unroll
    for(int j=0;j<8;++j) v[j] = acc[rr][j] + bb[j];
    *(float4*)&out[(size_t)r*128 + c0a] = make_float4(v[0],v[1],v[2],v[3]);
    *(float4*)&out[(size_t)r*128 + c0b] = make_float4(v[4],v[5],v[6],v[7]);
    if(pool_mode == 1){
      *(float4*)&pool[(size_t)r*256 + c0a] = make_float4(v[0],v[1],v[2],v[3]);
      *(float4*)&pool[(size_t)r*256 + c0b] = make_float4(v[4],v[5],v[6],v[7]);
    } else if(pool_mode == 2){
      float4 p0 = *(float4*)&pool[(size_t)r*256 + c0a];
      float4 p1 = *(float4*)&pool[(size_t)r*256 + c0b];
      p0.x+=v[0]; p0.y+=v[1]; p0.z+=v[2]; p0.w+=v[3];
      p1.x+=v[4]; p1.y+=v[5]; p1.z+=v[6]; p1.w+=v[7];
      *(float4*)&pool[(size_t)r*256 + c0a] = p0;
      *(float4*)&pool[(size_t)r*256 + c0b] = p1;
    }
    if(musum){
      #pragma unroll
      for(int j=0;j<8;++j){ cs[j] += v[j]; cq[j] += v[j]*v[j]; }
    }
    if(asrc){
      float s = 0.f, d = 0.f;
      #pragma unroll
      for(int j=0;j<8;++j){ s += v[j]*as8[j]; d += v[j]*ad8[j]; }
      #pragma unroll
      for(int off=1; off<16; off<<=1){ s += __shfl_xor(s, off, 64); d += __shfl_xor(d, off, 64); }
      if(cg == 0){ sd[r] = s; dd[r] = d; }
    }
  }
  if(musum){
    #pragma unroll
    for(int j=0;j<8;++j){
      int cj = (j<4) ? c0a+j : c0b+(j-4);
      atomicAdd(&ls[cj], cs[j]); atomicAdd(&lq[cj], cq[j]);
    }
    __syncthreads();
    if(t < 128){ atomicAdd(&musum[t], ls[t]); atomicAdd(&sqsum[t], lq[t]); }
  }
}

// ---------------- GIN layer 0: fully fused ----------------
// A-operand computed in registers (K=3): no global A loads, no staging
// needed; unchanged from R5 (never the bottleneck).
__global__ __launch_bounds__(256) void k_gin0(
    const float* __restrict__ y3,
    const float* __restrict__ W1, const float* __restrict__ b1,
    const float* __restrict__ bn_a, const float* __restrict__ bn_sh,
    const float* __restrict__ W2, const float* __restrict__ b2,
    float* __restrict__ outh, float* __restrict__ pool){
  __shared__ float sW[128][128];   // 64 KB, full W2
  __shared__ float sW1[3][128];
  __shared__ float ssb[128];
  int t = threadIdx.x;
  #pragma unroll
  for(int i=0;i<16;++i){
    int f = i*1024 + t*4;
    *(float4*)&sW[f>>7][f&127] = *(const float4*)&W2[f];
  }
  if(t < 128){
    float a = bn_a[t];
    sW1[0][t] = W1[t]*a; sW1[1][t] = W1[128+t]*a; sW1[2][t] = W1[256+t]*a;
    ssb[t] = b1[t]*a + bn_sh[t];
  }
  int row0 = blockIdx.x*128;
  int rg = t >> 4, cg = t & 15;
  int c0a = cg*4, c0b = 64 + cg*4;
  float ya[8], yb[8], yc[8];
  #pragma unroll
  for(int rr=0; rr<8; ++rr){
    const float* yp = y3 + (size_t)(row0 + rg*8 + rr)*3;
    ya[rr] = yp[0]; yb[rr] = yp[1]; yc[rr] = yp[2];
  }
  float acc[8][8];
  #pragma unroll
  for(int i=0;i<8;++i)
    #pragma unroll
    for(int j=0;j<8;++j) acc[i][j]=0.f;
  __syncthreads();

  #pragma unroll 1
  for(int ch=0; ch<32; ++ch){
    int k0 = ch*4;
    float4 wa = *(float4*)&sW1[0][k0];
    float4 wb = *(float4*)&sW1[1][k0];
    float4 wc = *(float4*)&sW1[2][k0];
    float4 sb = *(float4*)&ssb[k0];
    float av[8][4];
    #pragma unroll
    for(int rr=0; rr<8; ++rr){
      #pragma unroll
      for(int j=0; j<4; ++j){
        av[rr][j] = fmaxf(fmaf(ya[rr], f4get(wa,j),
                         fmaf(yb[rr], f4get(wb,j),
                         fmaf(yc[rr], f4get(wc,j), f4get(sb,j)))), 0.f);
      }
    }
    #pragma unroll
    for(int j=0; j<4; ++j){
      float4 w0 = *(float4*)&sW[k0+j][c0a];
      float4 w1 = *(float4*)&sW[k0+j][c0b];
      #pragma unroll
      for(int rr=0; rr<8; ++rr){
        float a = av[rr][j];
        acc[rr][0] = fmaf(a, w0.x, acc[rr][0]);
        acc[rr][1] = fmaf(a, w0.y, acc[rr][1]);
        acc[rr][2] = fmaf(a, w0.z, acc[rr][2]);
        acc[rr][3] = fmaf(a, w0.w, acc[rr][3]);
        acc[rr][4] = fmaf(a, w1.x, acc[rr][4]);
        acc[rr][5] = fmaf(a, w1.y, acc[rr][5]);
        acc[rr][6] = fmaf(a, w1.z, acc[rr][6]);
        acc[rr][7] = fmaf(a, w1.w, acc[rr][7]);
      }
    }
  }
  #pragma unroll
  for(int rr=0; rr<8; ++rr){
    int r = row0 + rg*8 + rr;
    float v[8];
    #pragma unroll
    for(int j=0;j<8;++j){
      int cj = (j<4) ? c0a+j : c0b+(j-4);
      v[j] = acc[rr][j] + b2[cj];
    }
    float4 v0 = make_float4(v[0],v[1],v[2],v[3]);
    float4 v1 = make_float4(v[4],v[5],v[6],v[7]);
    *(float4*)&outh[(size_t)r*128 + c0a] = v0;
    *(float4*)&outh[(size_t)r*128 + c0b] = v1;
    *(float4*)&pool[(size_t)r*256 + c0a] = v0;
    *(float4*)&pool[(size_t)r*256 + c0b] = v1;
  }
}

// ---------------- batchnorm finalize ----------------
// GIN0: reduce 500x9 partials, analytic var through W1
__global__ void k_bnfin3(const float* __restrict__ part,
                         const float* __restrict__ W1, const float* __restrict__ b1,
                         const float* __restrict__ g, const float* __restrict__ beta,
                         float* __restrict__ a, float* __restrict__ sh){
  __shared__ float red[9][128];
  int t = threadIdx.x;
  float acc[9];
  #pragma unroll
  for(int j=0;j<9;++j) acc[j]=0.f;
  for(int i=t; i<500; i+=128)
    #pragma unroll
    for(int j=0;j<9;++j) acc[j] += part[i*9+j];
  #pragma unroll
  for(int j=0;j<9;++j) red[j][t] = acc[j];
  __syncthreads();
  for(int off=64; off; off>>=1){
    if(t < off)
      #pragma unroll
      for(int j=0;j<9;++j) red[j][t] += red[j][t+off];
    __syncthreads();
  }
  int c = t;
  double inv = 1.0/NN;
  double m0=red[0][0]*inv, m1=red[1][0]*inv, m2=red[2][0]*inv;
  double C00=red[3][0]*inv-m0*m0, C01=red[4][0]*inv-m0*m1, C02=red[5][0]*inv-m0*m2;
  double C11=red[6][0]*inv-m1*m1, C12=red[7][0]*inv-m1*m2, C22=red[8][0]*inv-m2*m2;
  double w0=W1[c], w1=W1[128+c], w2=W1[256+c];
  double mu  = m0*w0 + m1*w1 + m2*w2 + (double)b1[c];
  double var = w0*w0*C00 + w1*w1*C11 + w2*w2*C22
             + 2.0*(w0*w1*C01 + w0*w2*C02 + w1*w2*C12);
  double ai = (double)g[c] / sqrt(var + 1e-5);
  a[c]  = (float)ai;
  sh[c] = (float)((double)beta[c] - mu*ai);
}
__global__ void k_bnfin(const float* __restrict__ musum, const float* __restrict__ sqsum,
                        const float* __restrict__ g, const float* __restrict__ beta,
                        float* __restrict__ a, float* __restrict__ sh){
  int c = threadIdx.x;
  float mu  = musum[c] * (1.f/NN);
  float var = sqsum[c] * (1.f/NN) - mu*mu;
  float ai  = g[c] / sqrtf(var + 1e-5f);
  a[c]  = ai;
  sh[c] = beta[c] - mu*ai;
}

// ---------------- pooling / output ----------------
__global__ __launch_bounds__(256) void k_gpool2(const float* __restrict__ h,
                                                float* __restrict__ gpool, float scale){
  __shared__ float s[128];
  int g = blockIdx.x >> 4, chunk = blockIdx.x & 15;
  int t = threadIdx.x, c = t & 127, hh = t >> 7;
  int r0 = g*NPG + chunk*125;
  float sm = 0.f;
  for(int r = r0 + hh; r < r0 + 125; r += 2) sm += h[(size_t)r*128 + c];
  if(hh == 1) s[c] = sm;
  __syncthreads();
  if(hh == 0) atomicAdd(&gpool[g*128 + c], (sm + s[c]) * scale);
}
__global__ void k_write_graph(const float* __restrict__ gpool, const float* __restrict__ gdg,
                              float* __restrict__ out){
  int i = blockIdx.x*256 + threadIdx.x;
  int g = i >> 8, c = i & 255;
  out[(size_t)NN*256 + i] = (c < 128) ? gpool[g*128 + c] : gdg[g*128 + c - 128];
}

// ---------------- launch ----------------
extern "C" void kernel_launch(void* const* d_in, const int* in_sizes, int n_in,
                              void* d_out, int out_size, void* d_ws, size_t ws_size,
                              hipStream_t stream){
  const float* x        = (const float*)d_in[0];
  const int*   ei       = (const int*)d_in[1];
  const int*   ei_pc    = (const int*)d_in[2];
  const int*   ei_mc    = (const int*)d_in[3];
  const float* gin0_W1  = (const float*)d_in[6];
  const float* gin0_b1  = (const float*)d_in[7];
  const float* gin0_g   = (const float*)d_in[8];
  const float* gin0_be  = (const float*)d_in[9];
  const float* gin0_W2  = (const float*)d_in[10];
  const float* gin0_b2  = (const float*)d_in[11];
  const float* ginr_W1  = (const float*)d_in[12];
  const float* ginr_b1  = (const float*)d_in[13];
  const float* ginr_g   = (const float*)d_in[14];
  const float* ginr_be  = (const float*)d_in[15];
  const float* ginr_W2  = (const float*)d_in[16];
  const float* ginr_b2  = (const float*)d_in[17];
  const float* gat0_W   = (const float*)d_in[18];
  const float* gat0_as  = (const float*)d_in[19];
  const float* gat0_ad  = (const float*)d_in[20];
  const float* gat0_b   = (const float*)d_in[21];
  const float* gatr_W   = (const float*)d_in[22];
  const float* gatr_as  = (const float*)d_in[23];
  const float* gatr_ad  = (const float*)d_in[24];
  const float* gatr_b   = (const float*)d_in[25];
  float* out = (float*)d_out;

  float* ws = (float*)d_ws;
  size_t o = 0;
  auto alloc_f = [&](size_t n){ float* p = ws + o; o += (n + 3) & ~(size_t)3; return p; };
  float* bufA   = alloc_f((size_t)NN*HH);
  float* bufB   = alloc_f((size_t)NN*HH);
  float* bufC   = alloc_f((size_t)NN*HH);
  int* rp_gin   = (int*)alloc_f(NN+1);
  int* col_gin  = (int*)alloc_f(EG);
  int* rp_pc    = (int*)alloc_f(NN+1);
  int* col_pc   = (int*)alloc_f(EPCV+NN);
  int* rp_mc    = (int*)alloc_f(NN+1);
  int* col_mc   = (int*)alloc_f(EPCV+NN);
  int* counts   = (int*)alloc_f(NN);
  int* bsums    = (int*)alloc_f(256);
  float* agg3   = alloc_f((size_t)NN*3);
  float* sd     = alloc_f(NN);
  float* dd     = alloc_f(NN);
  float* gpool  = alloc_f(GG*HH);     // gpool+gdg contiguous (one memset)
  float* gdg    = alloc_f(GG*HH);
  float* bnstat = alloc_f(256);
  float* bn_a   = alloc_f(128);
  float* bn_sh  = alloc_f(128);
  float* spart  = alloc_f(500*9 + 4);
  if(ws_size < o*sizeof(float)) return;

  dim3 B(256);
  dim3 gN((NN+255)/256);          // 500
  dim3 gWave(32000);
  dim3 gMM(1000), gMM3(16000);    // 128-row mm tiles
  dim3 gGP(GG*16);

  auto build_csr = [&](const int* s, const int* d, int E, int loops, int* rp, int* colarr){
    k_seti<<<gN, B, 0, stream>>>(counts, NN, loops ? 1 : 0);
    k_hist<<<dim3((E+255)/256), B, 0, stream>>>(d, E, counts);
    k_scan1<<<dim3(250), B, 0, stream>>>(counts, rp, bsums);
    k_scan2<<<dim3(1), B, 0, stream>>>(bsums, 250);
    k_scan3<<<gN, B, 0, stream>>>(rp, bsums);
    k_fill<<<gN, B, 0, stream>>>(rp, counts);
    k_scatter<<<dim3((E+255)/256), B, 0, stream>>>(s, d, E, counts, colarr);
    if(loops) k_scatter_loops<<<gN, B, 0, stream>>>(counts, colarr);
  };
  build_csr(ei,           ei + EG,       EG,   0, rp_gin, col_gin);
  build_csr(ei_pc,        ei_pc + EPCV,  EPCV, 1, rp_pc,  col_pc);
  build_csr(ei_mc,        ei_mc + EPCV,  EPCV, 1, rp_mc,  col_mc);

  k_setf<<<dim3(64), B, 0, stream>>>(gpool, 2*GG*HH);   // gpool + gdg

  // ---- GIN layer 0 (fully fused; BN stats analytic from [N,3] covariance) ----
  k_segmean3<<<gN, B, 0, stream>>>(x, rp_gin, col_gin, agg3, spart);
  k_bnfin3<<<dim3(1), dim3(128), 0, stream>>>(spart, gin0_W1, gin0_b1, gin0_g, gin0_be, bn_a, bn_sh);
  k_gin0<<<gMM, B, 0, stream>>>(agg3, gin0_W1, gin0_b1, bn_a, bn_sh, gin0_W2, gin0_b2, bufA, out);
  k_gpool2<<<gGP, B, 0, stream>>>(bufA, gpool, 1.f/NPG);

  // ---- GIN layers 1..3 ----
  for(int l=0; l<3; ++l){
    k_segmean128<<<gWave, B, 0, stream>>>(bufA, rp_gin, col_gin, bufB);
    k_setf<<<dim3(1), B, 0, stream>>>(bnstat, 256);
    k_mm128_t<false><<<gMM, B, 0, stream>>>(bufB, nullptr, nullptr,
                                   ginr_W1 + (size_t)l*HH*HH, ginr_b1 + l*HH, bufC, nullptr, 0,
                                   nullptr, nullptr, nullptr, nullptr, bnstat, bnstat+128);
    k_bnfin<<<dim3(1), dim3(128), 0, stream>>>(bnstat, bnstat+128, ginr_g + l*HH, ginr_be + l*HH, bn_a, bn_sh);
    k_mm128_t<true><<<gMM, B, 0, stream>>>(bufC, bn_a, bn_sh,
                                   ginr_W2 + (size_t)l*HH*HH, ginr_b2 + l*HH, bufA, out, 2,
                                   nullptr, nullptr, nullptr, nullptr, nullptr, nullptr);
    k_gpool2<<<gGP, B, 0, stream>>>(bufA, gpool, 1.f/NPG);
  }

  // ---- DGHAN layer 0 (in_dim = 3) ----
  k_mm3<<<gMM3, B, 0, stream>>>(x, gat0_W,          gat0_as,      gat0_ad,      sd, dd, bufB);
  k_gat_agg<<<gWave, B, 0, stream>>>(bufB, rp_pc, col_pc, sd, dd, bufC,
                                     nullptr, nullptr, nullptr, nullptr);
  k_mm3<<<gMM3, B, 0, stream>>>(x, gat0_W + 3*HH,   gat0_as + HH, gat0_ad + HH, sd, dd, bufB);
  k_gat_agg<<<gWave, B, 0, stream>>>(bufB, rp_mc, col_mc, sd, dd, bufA,
                                     bufC, gat0_b, gat0_b + HH, nullptr);

  // ---- DGHAN layers 1..3 ----
  for(int l=0; l<3; ++l){
    const float* Wl = gatr_W + (size_t)l*2*HH*HH;
    k_mm128_t<false><<<gMM, B, 0, stream>>>(bufA, nullptr, nullptr, Wl, nullptr, bufB, nullptr, 0,
                                   gatr_as + (size_t)(l*2)*HH, gatr_ad + (size_t)(l*2)*HH, sd, dd,
                                   nullptr, nullptr);
    k_gat_agg<<<gWave, B, 0, stream>>>(bufB, rp_pc, col_pc, sd, dd, bufC,
                                       nullptr, nullptr, nullptr, nullptr);
    k_mm128_t<false><<<gMM, B, 0, stream>>>(bufA, nullptr, nullptr, Wl + HH*HH, nullptr, bufB, nullptr, 0,
                                   gatr_as + (size_t)(l*2+1)*HH, gatr_ad + (size_t)(l*2+1)*HH, sd, dd,
                                   nullptr, nullptr);
    k_gat_agg<<<gWave, B, 0, stream>>>(bufB, rp_mc, col_mc, sd, dd, bufA,
                                       bufC, gatr_b + (size_t)(l*2)*HH, gatr_b + (size_t)(l*2+1)*HH,
                                       (l == 2) ? out : nullptr);
  }

  // ---- finals ----
  k_gpool2<<<gGP, B, 0, stream>>>(bufA, gdg, 1.f/NPG);
  k_write_graph<<<dim3(GG), B, 0, stream>>>(gpool, gdg, out);
}

// Round 7
// 2288.300 us; speedup vs baseline: 2.7733x; 1.1594x over previous
//
#include <hip/hip_runtime.h>
#include <cstdint>

#define NN 128000
#define GG 64
#define HH 128
#define EG 1024000
#define EPCV 512000
#define NPG 2000   // nodes per graph

static __device__ __forceinline__ float lrelu(float x){ return x > 0.f ? x : 0.2f*x; }
static __device__ __forceinline__ float f4get(const float4& v, int j){
  return j==0 ? v.x : j==1 ? v.y : j==2 ? v.z : v.w;
}

// ---------------- utility ----------------
__global__ void k_seti(int* p, int n, int v){
  int i = blockIdx.x*blockDim.x + threadIdx.x;
  if(i < n) p[i] = v;
}
__global__ void k_setf(float* p, int n){
  int i = blockIdx.x*blockDim.x + threadIdx.x;
  if(i < n) p[i] = 0.f;
}

// ---------------- CSR build ----------------
__global__ void k_hist(const int* __restrict__ dst, int E, int* __restrict__ counts){
  int i = blockIdx.x*blockDim.x + threadIdx.x;
  if(i < E) atomicAdd(&counts[dst[i]], 1);
}
__global__ void k_scan1(const int* __restrict__ counts, int* __restrict__ rowptr, int* __restrict__ bsums){
  __shared__ int lds[256];
  int t = threadIdx.x, b = blockIdx.x;
  int i0 = b*512 + t*2;
  int s0 = counts[i0], s1 = counts[i0+1];
  int pair = s0 + s1;
  lds[t] = pair; __syncthreads();
  for(int off=1; off<256; off<<=1){
    int v = (t >= off) ? lds[t-off] : 0;
    __syncthreads();
    lds[t] += v;
    __syncthreads();
  }
  int excl = lds[t] - pair;
  rowptr[i0+1] = excl + s0;
  rowptr[i0+2] = excl + pair;
  if(t == 255) bsums[b] = lds[t];
}
__global__ void k_scan2(int* bsums, int nb){
  __shared__ int lds[256];
  int t = threadIdx.x;
  int v = (t < nb) ? bsums[t] : 0;
  lds[t] = v; __syncthreads();
  for(int off=1; off<256; off<<=1){
    int u = (t >= off) ? lds[t-off] : 0;
    __syncthreads();
    lds[t] += u;
    __syncthreads();
  }
  if(t < nb) bsums[t] = lds[t] - v;   // exclusive
}
__global__ void k_scan3(int* __restrict__ rowptr, const int* __restrict__ bsums){
  int i = blockIdx.x*blockDim.x + threadIdx.x;
  if(i >= NN) return;
  rowptr[i+1] += bsums[i >> 9];
  if(i == 0) rowptr[0] = 0;
}
__global__ void k_fill(const int* __restrict__ rowptr, int* __restrict__ fill){
  int i = blockIdx.x*blockDim.x + threadIdx.x;
  if(i < NN) fill[i] = rowptr[i];
}
__global__ void k_scatter(const int* __restrict__ src, const int* __restrict__ dst, int E,
                          int* __restrict__ fill, int* __restrict__ colarr){
  int i = blockIdx.x*blockDim.x + threadIdx.x;
  if(i >= E) return;
  int pos = atomicAdd(&fill[dst[i]], 1);
  colarr[pos] = src[i];
}
__global__ void k_scatter_loops(int* __restrict__ fill, int* __restrict__ colarr){
  int i = blockIdx.x*blockDim.x + threadIdx.x;
  if(i >= NN) return;
  int pos = atomicAdd(&fill[i], 1);
  colarr[pos] = i;
}

// ---------------- aggregation ----------------
// y = x + mean_{j->i} x_j ; fused BN-stat partials (9 per block, no atomics)
__global__ __launch_bounds__(256) void k_segmean3(const float* __restrict__ x, const int* __restrict__ rp,
                           const int* __restrict__ col, float* __restrict__ y,
                           float* __restrict__ part){
  __shared__ float sp[4][9];
  int i = blockIdx.x*256 + threadIdx.x;   // 500*256 == NN exactly
  int b = rp[i], e = rp[i+1];
  float a0=0.f, a1=0.f, a2=0.f;
  for(int j=b; j<e; ++j){
    int s = col[j];
    a0 += x[s*3]; a1 += x[s*3+1]; a2 += x[s*3+2];
  }
  float inv = 1.f / fmaxf((float)(e-b), 1.f);
  float y0 = x[i*3]   + a0*inv;
  float y1 = x[i*3+1] + a1*inv;
  float y2 = x[i*3+2] + a2*inv;
  y[i*3] = y0; y[i*3+1] = y1; y[i*3+2] = y2;
  float p[9] = {y0,y1,y2, y0*y0,y0*y1,y0*y2, y1*y1,y1*y2, y2*y2};
  #pragma unroll
  for(int off=1; off<64; off<<=1)
    #pragma unroll
    for(int j=0;j<9;++j) p[j] += __shfl_xor(p[j], off, 64);
  int lane = threadIdx.x & 63, wv = threadIdx.x >> 6;
  if(lane == 0)
    #pragma unroll
    for(int j=0;j<9;++j) sp[wv][j] = p[j];
  __syncthreads();
  int t = threadIdx.x;
  if(t < 9) part[blockIdx.x*9 + t] = sp[0][t] + sp[1][t] + sp[2][t] + sp[3][t];
}

// ---- gather kernels v2: 2 nodes/wave (32 lanes x float4) + 2-way edge
// unroll. R6 diagnosis: one-wave-per-node had ONE 512B row in flight per
// wave (serial col->row dependent chain, ~5 iters) -> latency-bound at
// 2.65 TB/s (33% peak) with VALUBusy 45%. 2 groups/wave x 2 rows in
// flight = 4x MLP, same traffic.

// y = h + mean (fused self add)
__global__ __launch_bounds__(256) void k_segmean128(const float* __restrict__ h, const int* __restrict__ rp,
                             const int* __restrict__ col, float* __restrict__ y){
  int gid = blockIdx.x*256 + threadIdx.x;
  int w = gid >> 5, c0 = (gid & 31)*4;    // 16000 blocks * 8 groups == NN
  int b = rp[w], e = rp[w+1];
  float ax=0.f, ay=0.f, az=0.f, aw=0.f;
  int j = b;
  for(; j+2 <= e; j += 2){
    int s0 = col[j], s1 = col[j+1];
    float4 v0 = *(const float4*)(h + (size_t)s0*HH + c0);
    float4 v1 = *(const float4*)(h + (size_t)s1*HH + c0);
    ax += v0.x + v1.x; ay += v0.y + v1.y;
    az += v0.z + v1.z; aw += v0.w + v1.w;
  }
  if(j < e){
    int s0 = col[j];
    float4 v0 = *(const float4*)(h + (size_t)s0*HH + c0);
    ax += v0.x; ay += v0.y; az += v0.z; aw += v0.w;
  }
  float inv = 1.f / fmaxf((float)(e-b), 1.f);
  float4 self = *(const float4*)(h + (size_t)w*HH + c0);
  float4 o;
  o.x = self.x + ax*inv; o.y = self.y + ay*inv;
  o.z = self.z + az*inv; o.w = self.w + aw*inv;
  *(float4*)(y + (size_t)w*HH + c0) = o;
}

// GAT softmax-aggregate, single pass (no max-subtraction: logits << 80 here;
// fp32 exp safe, clamp is overflow guard only). Optional fused combine.
__global__ __launch_bounds__(256) void k_gat_agg(const float* __restrict__ hW, const int* __restrict__ rp,
                          const int* __restrict__ col, const float* __restrict__ sd,
                          const float* __restrict__ ddv, float* __restrict__ out,
                          const float* __restrict__ P, const float* __restrict__ bpc,
                          const float* __restrict__ bmc, float* __restrict__ out2){
  int gid = blockIdx.x*256 + threadIdx.x;
  int w = gid >> 5, c0 = (gid & 31)*4;
  int b = rp[w], e = rp[w+1];
  float dv = ddv[w];
  float s = 0.f, ax=0.f, ay=0.f, az=0.f, aw=0.f;
  int j = b;
  for(; j+2 <= e; j += 2){
    int sc0 = col[j], sc1 = col[j+1];
    float wt0 = expf(fminf(lrelu(sd[sc0] + dv), 80.f));
    float wt1 = expf(fminf(lrelu(sd[sc1] + dv), 80.f));
    float4 v0 = *(const float4*)(hW + (size_t)sc0*HH + c0);
    float4 v1 = *(const float4*)(hW + (size_t)sc1*HH + c0);
    s += wt0 + wt1;
    ax += wt0*v0.x + wt1*v1.x; ay += wt0*v0.y + wt1*v1.y;
    az += wt0*v0.z + wt1*v1.z; aw += wt0*v0.w + wt1*v1.w;
  }
  if(j < e){
    int sc0 = col[j];
    float wt0 = expf(fminf(lrelu(sd[sc0] + dv), 80.f));
    float4 v0 = *(const float4*)(hW + (size_t)sc0*HH + c0);
    s += wt0;
    ax += wt0*v0.x; ay += wt0*v0.y; az += wt0*v0.z; aw += wt0*v0.w;
  }
  float inv = 1.f / (s + 1e-16f);
  ax *= inv; ay *= inv; az *= inv; aw *= inv;
  if(P){
    float4 p  = *(const float4*)(P + (size_t)w*HH + c0);
    float4 bp = *(const float4*)(bpc + c0);
    float4 bm = *(const float4*)(bmc + c0);
    float a0 = p.x + bp.x; a0 = a0 > 0.f ? a0 : expm1f(a0);
    float a1 = p.y + bp.y; a1 = a1 > 0.f ? a1 : expm1f(a1);
    float a2 = p.z + bp.z; a2 = a2 > 0.f ? a2 : expm1f(a2);
    float a3 = p.w + bp.w; a3 = a3 > 0.f ? a3 : expm1f(a3);
    float b0 = ax + bm.x;  b0 = b0 > 0.f ? b0 : expm1f(b0);
    float b1 = ay + bm.y;  b1 = b1 > 0.f ? b1 : expm1f(b1);
    float b2 = az + bm.z;  b2 = b2 > 0.f ? b2 : expm1f(b2);
    float b3 = aw + bm.w;  b3 = b3 > 0.f ? b3 : expm1f(b3);
    float4 o = make_float4(0.5f*(a0+b0), 0.5f*(a1+b1), 0.5f*(a2+b2), 0.5f*(a3+b3));
    *(float4*)(out + (size_t)w*HH + c0) = o;
    if(out2) *(float4*)&out2[(size_t)w*256 + 128 + c0] = o;
  } else {
    *(float4*)(out + (size_t)w*HH + c0) = make_float4(ax, ay, az, aw);
  }
}

// ---------------- matmuls ----------------
// K=3 matmul with fused attention dots
__global__ __launch_bounds__(256) void k_mm3(const float* __restrict__ A,
        const float* __restrict__ W,
        const float* __restrict__ asrc, const float* __restrict__ adst,
        float* __restrict__ sd, float* __restrict__ dd, float* __restrict__ out){
  int t = threadIdx.x;
  int r = blockIdx.x*8 + (t >> 5);
  int lane = t & 31, c0 = lane*4;
  float a0 = A[r*3], a1 = A[r*3+1], a2 = A[r*3+2];
  float v[4];
  #pragma unroll
  for(int j=0; j<4; ++j){
    int c = c0 + j;
    v[j] = a0*W[c] + a1*W[128+c] + a2*W[256+c];
  }
  *(float4*)&out[(size_t)r*128 + c0] = make_float4(v[0],v[1],v[2],v[3]);
  float s = 0.f, d = 0.f;
  #pragma unroll
  for(int j=0; j<4; ++j){ s += v[j]*asrc[c0+j]; d += v[j]*adst[c0+j]; }
  #pragma unroll
  for(int off=1; off<32; off<<=1){ s += __shfl_xor(s, off, 64); d += __shfl_xor(d, off, 64); }
  if(lane == 0){ sd[r] = s; dd[r] = d; }
}

// ---- K=128 matmul, v5: LDS-deduped A (validated R6: mm dropped out of
// top-5). Coalesced A stage through double-buffered sA; 16 VMEM
// instrs/thread; W split-column resident (0 conflicts). ----

#define MM_COMPUTE_CH(BUFIDX, K0) { \
  _Pragma("unroll") \
  for(int j_=0; j_<8; ++j_){ \
    float4 a0 = *(float4*)&sA[BUFIDX][j_][rg8]; \
    float4 a1 = *(float4*)&sA[BUFIDX][j_][rg8+4]; \
    float4 w0 = *(float4*)&sW[(K0)+j_][c0a]; \
    float4 w1 = *(float4*)&sW[(K0)+j_][c0b]; \
    float ar[8] = {a0.x,a0.y,a0.z,a0.w,a1.x,a1.y,a1.z,a1.w}; \
    _Pragma("unroll") \
    for(int rr_=0; rr_<8; ++rr_){ \
      acc[rr_][0] = fmaf(ar[rr_], w0.x, acc[rr_][0]); \
      acc[rr_][1] = fmaf(ar[rr_], w0.y, acc[rr_][1]); \
      acc[rr_][2] = fmaf(ar[rr_], w0.z, acc[rr_][2]); \
      acc[rr_][3] = fmaf(ar[rr_], w0.w, acc[rr_][3]); \
      acc[rr_][4] = fmaf(ar[rr_], w1.x, acc[rr_][4]); \
      acc[rr_][5] = fmaf(ar[rr_], w1.y, acc[rr_][5]); \
      acc[rr_][6] = fmaf(ar[rr_], w1.z, acc[rr_][6]); \
      acc[rr_][7] = fmaf(ar[rr_], w1.w, acc[rr_][7]); \
    } \
  } }

template<bool HASBN>
__global__ __launch_bounds__(256) void k_mm128_t(
    const float* __restrict__ A,
    const float* __restrict__ bn_a, const float* __restrict__ bn_sh,
    const float* __restrict__ W, const float* __restrict__ bias,
    float* __restrict__ out, float* __restrict__ pool, int pool_mode,
    const float* __restrict__ asrc, const float* __restrict__ adst,
    float* __restrict__ sd, float* __restrict__ dd,
    float* __restrict__ musum, float* __restrict__ sqsum){
  __shared__ float sW[128][128];     // 64 KB, full W
  __shared__ float sA[2][8][128];    // 8 KB, double-buffered A chunk (k-major)
  __shared__ float sBNa[128], sBNsh[128];
  __shared__ float ls[128], lq[128];
  int t = threadIdx.x;
  #pragma unroll
  for(int i=0;i<16;++i){
    int f = i*1024 + t*4;
    *(float4*)&sW[f>>7][f&127] = *(const float4*)&W[f];
  }
  if(HASBN && t < 128){ sBNa[t] = bn_a[t]; sBNsh[t] = bn_sh[t]; }
  if(musum && t < 128){ ls[t] = 0.f; lq[t] = 0.f; }
  int row0 = blockIdx.x*128;
  int rg = t >> 4, cg = t & 15;
  int rg8 = rg*8;
  int c0a = cg*4, c0b = 64 + cg*4;
  int lrow = t >> 1, lk = (t & 1)*4;   // staging: row, k-half within chunk
  const float* ap = A + (size_t)(row0 + lrow)*HH + lk;
  float acc[8][8];
  #pragma unroll
  for(int i=0;i<8;++i)
    #pragma unroll
    for(int j=0;j<8;++j) acc[i][j]=0.f;
  float4 lv = *(const float4*)ap;      // chunk 0
  __syncthreads();                     // W/BN staged; sA untouched yet

  #pragma unroll 1
  for(int ch=0; ch<16; ++ch){
    int b = ch & 1;
    float4 nlv = lv;
    if(ch < 15) nlv = *(const float4*)(ap + (ch+1)*8);   // prefetch next chunk
    float4 sv = lv;
    if(HASBN){
      float4 ba = *(float4*)&sBNa[ch*8 + lk];
      float4 bs = *(float4*)&sBNsh[ch*8 + lk];
      sv.x = fmaxf(fmaf(sv.x, ba.x, bs.x), 0.f);
      sv.y = fmaxf(fmaf(sv.y, ba.y, bs.y), 0.f);
      sv.z = fmaxf(fmaf(sv.z, ba.z, bs.z), 0.f);
      sv.w = fmaxf(fmaf(sv.w, ba.w, bs.w), 0.f);
    }
    sA[b][lk  ][lrow] = sv.x;
    sA[b][lk+1][lrow] = sv.y;
    sA[b][lk+2][lrow] = sv.z;
    sA[b][lk+3][lrow] = sv.w;
    __syncthreads();                   // writes of buf b visible
    MM_COMPUTE_CH(b, ch*8);
    lv = nlv;
  }

  // ---- epilogues (unchanged semantics, split-column indexing) ----
  float as8[8], ad8[8];
  if(asrc){
    #pragma unroll
    for(int j=0;j<8;++j){
      int cj = (j<4) ? c0a+j : c0b+(j-4);
      as8[j] = asrc[cj]; ad8[j] = adst[cj];
    }
  }
  float bb[8];
  #pragma unroll
  for(int j=0;j<8;++j){
    int cj = (j<4) ? c0a+j : c0b+(j-4);
    bb[j] = bias ? bias[cj] : 0.f;
  }
  float cs[8], cq[8];
  #pragma unroll
  for(int j=0;j<8;++j){ cs[j]=0.f; cq[j]=0.f; }
  #pragma unroll
  for(int rr=0; rr<8; ++rr){
    int r = row0 + rg8 + rr;
    float v[8];
    #pragma unroll
    for(int j=0;j<8;++j) v[j] = acc[rr][j] + bb[j];
    *(float4*)&out[(size_t)r*128 + c0a] = make_float4(v[0],v[1],v[2],v[3]);
    *(float4*)&out[(size_t)r*128 + c0b] = make_float4(v[4],v[5],v[6],v[7]);
    if(pool_mode == 1){
      *(float4*)&pool[(size_t)r*256 + c0a] = make_float4(v[0],v[1],v[2],v[3]);
      *(float4*)&pool[(size_t)r*256 + c0b] = make_float4(v[4],v[5],v[6],v[7]);
    } else if(pool_mode == 2){
      float4 p0 = *(float4*)&pool[(size_t)r*256 + c0a];
      float4 p1 = *(float4*)&pool[(size_t)r*256 + c0b];
      p0.x+=v[0]; p0.y+=v[1]; p0.z+=v[2]; p0.w+=v[3];
      p1.x+=v[4]; p1.y+=v[5]; p1.z+=v[6]; p1.w+=v[7];
      *(float4*)&pool[(size_t)r*256 + c0a] = p0;
      *(float4*)&pool[(size_t)r*256 + c0b] = p1;
    }
    if(musum){
      #pragma unroll
      for(int j=0;j<8;++j){ cs[j] += v[j]; cq[j] += v[j]*v[j]; }
    }
    if(asrc){
      float s = 0.f, d = 0.f;
      #pragma unroll
      for(int j=0;j<8;++j){ s += v[j]*as8[j]; d += v[j]*ad8[j]; }
      #pragma unroll
      for(int off=1; off<16; off<<=1){ s += __shfl_xor(s, off, 64); d += __shfl_xor(d, off, 64); }
      if(cg == 0){ sd[r] = s; dd[r] = d; }
    }
  }
  if(musum){
    #pragma unroll
    for(int j=0;j<8;++j){
      int cj = (j<4) ? c0a+j : c0b+(j-4);
      atomicAdd(&ls[cj], cs[j]); atomicAdd(&lq[cj], cq[j]);
    }
    __syncthreads();
    if(t < 128){ atomicAdd(&musum[t], ls[t]); atomicAdd(&sqsum[t], lq[t]); }
  }
}

// ---------------- GIN layer 0: fully fused ----------------
__global__ __launch_bounds__(256) void k_gin0(
    const float* __restrict__ y3,
    const float* __restrict__ W1, const float* __restrict__ b1,
    const float* __restrict__ bn_a, const float* __restrict__ bn_sh,
    const float* __restrict__ W2, const float* __restrict__ b2,
    float* __restrict__ outh, float* __restrict__ pool){
  __shared__ float sW[128][128];   // 64 KB, full W2
  __shared__ float sW1[3][128];
  __shared__ float ssb[128];
  int t = threadIdx.x;
  #pragma unroll
  for(int i=0;i<16;++i){
    int f = i*1024 + t*4;
    *(float4*)&sW[f>>7][f&127] = *(const float4*)&W2[f];
  }
  if(t < 128){
    float a = bn_a[t];
    sW1[0][t] = W1[t]*a; sW1[1][t] = W1[128+t]*a; sW1[2][t] = W1[256+t]*a;
    ssb[t] = b1[t]*a + bn_sh[t];
  }
  int row0 = blockIdx.x*128;
  int rg = t >> 4, cg = t & 15;
  int c0a = cg*4, c0b = 64 + cg*4;
  float ya[8], yb[8], yc[8];
  #pragma unroll
  for(int rr=0; rr<8; ++rr){
    const float* yp = y3 + (size_t)(row0 + rg*8 + rr)*3;
    ya[rr] = yp[0]; yb[rr] = yp[1]; yc[rr] = yp[2];
  }
  float acc[8][8];
  #pragma unroll
  for(int i=0;i<8;++i)
    #pragma unroll
    for(int j=0;j<8;++j) acc[i][j]=0.f;
  __syncthreads();

  #pragma unroll 1
  for(int ch=0; ch<32; ++ch){
    int k0 = ch*4;
    float4 wa = *(float4*)&sW1[0][k0];
    float4 wb = *(float4*)&sW1[1][k0];
    float4 wc = *(float4*)&sW1[2][k0];
    float4 sb = *(float4*)&ssb[k0];
    float av[8][4];
    #pragma unroll
    for(int rr=0; rr<8; ++rr){
      #pragma unroll
      for(int j=0; j<4; ++j){
        av[rr][j] = fmaxf(fmaf(ya[rr], f4get(wa,j),
                         fmaf(yb[rr], f4get(wb,j),
                         fmaf(yc[rr], f4get(wc,j), f4get(sb,j)))), 0.f);
      }
    }
    #pragma unroll
    for(int j=0; j<4; ++j){
      float4 w0 = *(float4*)&sW[k0+j][c0a];
      float4 w1 = *(float4*)&sW[k0+j][c0b];
      #pragma unroll
      for(int rr=0; rr<8; ++rr){
        float a = av[rr][j];
        acc[rr][0] = fmaf(a, w0.x, acc[rr][0]);
        acc[rr][1] = fmaf(a, w0.y, acc[rr][1]);
        acc[rr][2] = fmaf(a, w0.z, acc[rr][2]);
        acc[rr][3] = fmaf(a, w0.w, acc[rr][3]);
        acc[rr][4] = fmaf(a, w1.x, acc[rr][4]);
        acc[rr][5] = fmaf(a, w1.y, acc[rr][5]);
        acc[rr][6] = fmaf(a, w1.z, acc[rr][6]);
        acc[rr][7] = fmaf(a, w1.w, acc[rr][7]);
      }
    }
  }
  #pragma unroll
  for(int rr=0; rr<8; ++rr){
    int r = row0 + rg*8 + rr;
    float v[8];
    #pragma unroll
    for(int j=0;j<8;++j){
      int cj = (j<4) ? c0a+j : c0b+(j-4);
      v[j] = acc[rr][j] + b2[cj];
    }
    float4 v0 = make_float4(v[0],v[1],v[2],v[3]);
    float4 v1 = make_float4(v[4],v[5],v[6],v[7]);
    *(float4*)&outh[(size_t)r*128 + c0a] = v0;
    *(float4*)&outh[(size_t)r*128 + c0b] = v1;
    *(float4*)&pool[(size_t)r*256 + c0a] = v0;
    *(float4*)&pool[(size_t)r*256 + c0b] = v1;
  }
}

// ---------------- batchnorm finalize ----------------
__global__ void k_bnfin3(const float* __restrict__ part,
                         const float* __restrict__ W1, const float* __restrict__ b1,
                         const float* __restrict__ g, const float* __restrict__ beta,
                         float* __restrict__ a, float* __restrict__ sh){
  __shared__ float red[9][128];
  int t = threadIdx.x;
  float acc[9];
  #pragma unroll
  for(int j=0;j<9;++j) acc[j]=0.f;
  for(int i=t; i<500; i+=128)
    #pragma unroll
    for(int j=0;j<9;++j) acc[j] += part[i*9+j];
  #pragma unroll
  for(int j=0;j<9;++j) red[j][t] = acc[j];
  __syncthreads();
  for(int off=64; off; off>>=1){
    if(t < off)
      #pragma unroll
      for(int j=0;j<9;++j) red[j][t] += red[j][t+off];
    __syncthreads();
  }
  int c = t;
  double inv = 1.0/NN;
  double m0=red[0][0]*inv, m1=red[1][0]*inv, m2=red[2][0]*inv;
  double C00=red[3][0]*inv-m0*m0, C01=red[4][0]*inv-m0*m1, C02=red[5][0]*inv-m0*m2;
  double C11=red[6][0]*inv-m1*m1, C12=red[7][0]*inv-m1*m2, C22=red[8][0]*inv-m2*m2;
  double w0=W1[c], w1=W1[128+c], w2=W1[256+c];
  double mu  = m0*w0 + m1*w1 + m2*w2 + (double)b1[c];
  double var = w0*w0*C00 + w1*w1*C11 + w2*w2*C22
             + 2.0*(w0*w1*C01 + w0*w2*C02 + w1*w2*C12);
  double ai = (double)g[c] / sqrt(var + 1e-5);
  a[c]  = (float)ai;
  sh[c] = (float)((double)beta[c] - mu*ai);
}
__global__ void k_bnfin(const float* __restrict__ musum, const float* __restrict__ sqsum,
                        const float* __restrict__ g, const float* __restrict__ beta,
                        float* __restrict__ a, float* __restrict__ sh){
  int c = threadIdx.x;
  float mu  = musum[c] * (1.f/NN);
  float var = sqsum[c] * (1.f/NN) - mu*mu;
  float ai  = g[c] / sqrtf(var + 1e-5f);
  a[c]  = ai;
  sh[c] = beta[c] - mu*ai;
}

// ---------------- pooling / output ----------------
__global__ __launch_bounds__(256) void k_gpool2(const float* __restrict__ h,
                                                float* __restrict__ gpool, float scale){
  __shared__ float s[128];
  int g = blockIdx.x >> 4, chunk = blockIdx.x & 15;
  int t = threadIdx.x, c = t & 127, hh = t >> 7;
  int r0 = g*NPG + chunk*125;
  float sm = 0.f;
  for(int r = r0 + hh; r < r0 + 125; r += 2) sm += h[(size_t)r*128 + c];
  if(hh == 1) s[c] = sm;
  __syncthreads();
  if(hh == 0) atomicAdd(&gpool[g*128 + c], (sm + s[c]) * scale);
}
__global__ void k_write_graph(const float* __restrict__ gpool, const float* __restrict__ gdg,
                              float* __restrict__ out){
  int i = blockIdx.x*256 + threadIdx.x;
  int g = i >> 8, c = i & 255;
  out[(size_t)NN*256 + i] = (c < 128) ? gpool[g*128 + c] : gdg[g*128 + c - 128];
}

// ---------------- launch ----------------
extern "C" void kernel_launch(void* const* d_in, const int* in_sizes, int n_in,
                              void* d_out, int out_size, void* d_ws, size_t ws_size,
                              hipStream_t stream){
  const float* x        = (const float*)d_in[0];
  const int*   ei       = (const int*)d_in[1];
  const int*   ei_pc    = (const int*)d_in[2];
  const int*   ei_mc    = (const int*)d_in[3];
  const float* gin0_W1  = (const float*)d_in[6];
  const float* gin0_b1  = (const float*)d_in[7];
  const float* gin0_g   = (const float*)d_in[8];
  const float* gin0_be  = (const float*)d_in[9];
  const float* gin0_W2  = (const float*)d_in[10];
  const float* gin0_b2  = (const float*)d_in[11];
  const float* ginr_W1  = (const float*)d_in[12];
  const float* ginr_b1  = (const float*)d_in[13];
  const float* ginr_g   = (const float*)d_in[14];
  const float* ginr_be  = (const float*)d_in[15];
  const float* ginr_W2  = (const float*)d_in[16];
  const float* ginr_b2  = (const float*)d_in[17];
  const float* gat0_W   = (const float*)d_in[18];
  const float* gat0_as  = (const float*)d_in[19];
  const float* gat0_ad  = (const float*)d_in[20];
  const float* gat0_b   = (const float*)d_in[21];
  const float* gatr_W   = (const float*)d_in[22];
  const float* gatr_as  = (const float*)d_in[23];
  const float* gatr_ad  = (const float*)d_in[24];
  const float* gatr_b   = (const float*)d_in[25];
  float* out = (float*)d_out;

  float* ws = (float*)d_ws;
  size_t o = 0;
  auto alloc_f = [&](size_t n){ float* p = ws + o; o += (n + 3) & ~(size_t)3; return p; };
  float* bufA   = alloc_f((size_t)NN*HH);
  float* bufB   = alloc_f((size_t)NN*HH);
  float* bufC   = alloc_f((size_t)NN*HH);
  int* rp_gin   = (int*)alloc_f(NN+1);
  int* col_gin  = (int*)alloc_f(EG);
  int* rp_pc    = (int*)alloc_f(NN+1);
  int* col_pc   = (int*)alloc_f(EPCV+NN);
  int* rp_mc    = (int*)alloc_f(NN+1);
  int* col_mc   = (int*)alloc_f(EPCV+NN);
  int* counts   = (int*)alloc_f(NN);
  int* bsums    = (int*)alloc_f(256);
  float* agg3   = alloc_f((size_t)NN*3);
  float* sd     = alloc_f(NN);
  float* dd     = alloc_f(NN);
  float* gpool  = alloc_f(GG*HH);     // gpool+gdg contiguous (one memset)
  float* gdg    = alloc_f(GG*HH);
  float* bnstat = alloc_f(256);
  float* bn_a   = alloc_f(128);
  float* bn_sh  = alloc_f(128);
  float* spart  = alloc_f(500*9 + 4);
  if(ws_size < o*sizeof(float)) return;

  dim3 B(256);
  dim3 gN((NN+255)/256);          // 500
  dim3 gHalf(16000);              // gather kernels: 2 nodes/wave
  dim3 gMM(1000), gMM3(16000);    // 128-row mm tiles
  dim3 gGP(GG*16);

  auto build_csr = [&](const int* s, const int* d, int E, int loops, int* rp, int* colarr){
    k_seti<<<gN, B, 0, stream>>>(counts, NN, loops ? 1 : 0);
    k_hist<<<dim3((E+255)/256), B, 0, stream>>>(d, E, counts);
    k_scan1<<<dim3(250), B, 0, stream>>>(counts, rp, bsums);
    k_scan2<<<dim3(1), B, 0, stream>>>(bsums, 250);
    k_scan3<<<gN, B, 0, stream>>>(rp, bsums);
    k_fill<<<gN, B, 0, stream>>>(rp, counts);
    k_scatter<<<dim3((E+255)/256), B, 0, stream>>>(s, d, E, counts, colarr);
    if(loops) k_scatter_loops<<<gN, B, 0, stream>>>(counts, colarr);
  };
  build_csr(ei,           ei + EG,       EG,   0, rp_gin, col_gin);
  build_csr(ei_pc,        ei_pc + EPCV,  EPCV, 1, rp_pc,  col_pc);
  build_csr(ei_mc,        ei_mc + EPCV,  EPCV, 1, rp_mc,  col_mc);

  k_setf<<<dim3(64), B, 0, stream>>>(gpool, 2*GG*HH);   // gpool + gdg

  // ---- GIN layer 0 (fully fused; BN stats analytic from [N,3] covariance) ----
  k_segmean3<<<gN, B, 0, stream>>>(x, rp_gin, col_gin, agg3, spart);
  k_bnfin3<<<dim3(1), dim3(128), 0, stream>>>(spart, gin0_W1, gin0_b1, gin0_g, gin0_be, bn_a, bn_sh);
  k_gin0<<<gMM, B, 0, stream>>>(agg3, gin0_W1, gin0_b1, bn_a, bn_sh, gin0_W2, gin0_b2, bufA, out);
  k_gpool2<<<gGP, B, 0, stream>>>(bufA, gpool, 1.f/NPG);

  // ---- GIN layers 1..3 ----
  for(int l=0; l<3; ++l){
    k_segmean128<<<gHalf, B, 0, stream>>>(bufA, rp_gin, col_gin, bufB);
    k_setf<<<dim3(1), B, 0, stream>>>(bnstat, 256);
    k_mm128_t<false><<<gMM, B, 0, stream>>>(bufB, nullptr, nullptr,
                                   ginr_W1 + (size_t)l*HH*HH, ginr_b1 + l*HH, bufC, nullptr, 0,
                                   nullptr, nullptr, nullptr, nullptr, bnstat, bnstat+128);
    k_bnfin<<<dim3(1), dim3(128), 0, stream>>>(bnstat, bnstat+128, ginr_g + l*HH, ginr_be + l*HH, bn_a, bn_sh);
    k_mm128_t<true><<<gMM, B, 0, stream>>>(bufC, bn_a, bn_sh,
                                   ginr_W2 + (size_t)l*HH*HH, ginr_b2 + l*HH, bufA, out, 2,
                                   nullptr, nullptr, nullptr, nullptr, nullptr, nullptr);
    k_gpool2<<<gGP, B, 0, stream>>>(bufA, gpool, 1.f/NPG);
  }

  // ---- DGHAN layer 0 (in_dim = 3) ----
  k_mm3<<<gMM3, B, 0, stream>>>(x, gat0_W,          gat0_as,      gat0_ad,      sd, dd, bufB);
  k_gat_agg<<<gHalf, B, 0, stream>>>(bufB, rp_pc, col_pc, sd, dd, bufC,
                                     nullptr, nullptr, nullptr, nullptr);
  k_mm3<<<gMM3, B, 0, stream>>>(x, gat0_W + 3*HH,   gat0_as + HH, gat0_ad + HH, sd, dd, bufB);
  k_gat_agg<<<gHalf, B, 0, stream>>>(bufB, rp_mc, col_mc, sd, dd, bufA,
                                     bufC, gat0_b, gat0_b + HH, nullptr);

  // ---- DGHAN layers 1..3 ----
  for(int l=0; l<3; ++l){
    const float* Wl = gatr_W + (size_t)l*2*HH*HH;
    k_mm128_t<false><<<gMM, B, 0, stream>>>(bufA, nullptr, nullptr, Wl, nullptr, bufB, nullptr, 0,
                                   gatr_as + (size_t)(l*2)*HH, gatr_ad + (size_t)(l*2)*HH, sd, dd,
                                   nullptr, nullptr);
    k_gat_agg<<<gHalf, B, 0, stream>>>(bufB, rp_pc, col_pc, sd, dd, bufC,
                                       nullptr, nullptr, nullptr, nullptr);
    k_mm128_t<false><<<gMM, B, 0, stream>>>(bufA, nullptr, nullptr, Wl + HH*HH, nullptr, bufB, nullptr, 0,
                                   gatr_as + (size_t)(l*2+1)*HH, gatr_ad + (size_t)(l*2+1)*HH, sd, dd,
                                   nullptr, nullptr);
    k_gat_agg<<<gHalf, B, 0, stream>>>(bufB, rp_mc, col_mc, sd, dd, bufA,
                                       bufC, gatr_b + (size_t)(l*2)*HH, gatr_b + (size_t)(l*2+1)*HH,
                                       (l == 2) ? out : nullptr);
  }

  // ---- finals ----
  k_gpool2<<<gGP, B, 0, stream>>>(bufA, gdg, 1.f/NPG);
  k_write_graph<<<dim3(GG), B, 0, stream>>>(gpool, gdg, out);
}